// Round 5
// baseline (410.633 us; speedup 1.0000x reference)
//
#include <hip/hip_runtime.h>

// GeneticDosageGNN: 3x GraphConv(+BN+ReLU) -> mean pool -> linear head
// N=50000 nodes, E=800000 edges, dims 128->256->128->64->3, 64 graphs.
// R5: latency-optimized gather: 4/8 edge-parallel lane groups, 16B loads/lane.

typedef __attribute__((ext_vector_type(8))) short    bf16x8;
typedef __attribute__((ext_vector_type(4))) float    f32x4;
typedef __attribute__((ext_vector_type(8))) unsigned short ush8;
typedef __attribute__((ext_vector_type(4))) unsigned short ush4;

__device__ __forceinline__ unsigned short f2b(float f) {
    union { float f; unsigned int u; } c; c.f = f;
    unsigned int u = c.u;
    return (unsigned short)((u + 0x7fffu + ((u >> 16) & 1u)) >> 16);
}
__device__ __forceinline__ float b2f(unsigned short h) {
    union { unsigned int u; float f; } c; c.u = ((unsigned int)h) << 16;
    return c.f;
}

// ---------------- CSR build ----------------

__global__ __launch_bounds__(256)
void hist_kernel(const int* __restrict__ dst, int* __restrict__ cnt, int E) {
    int i = blockIdx.x * blockDim.x + threadIdx.x;
    if (i < E) atomicAdd(&cnt[dst[i]], 1);
}

// scan phase 1: per-block (1024 counts) reduction
__global__ __launch_bounds__(256)
void scan1_kernel(const int* __restrict__ cnt, int* __restrict__ bsum, int N) {
    __shared__ int red[256];
    int base = blockIdx.x * 1024;
    int t = threadIdx.x;
    int s = 0;
#pragma unroll
    for (int j = 0; j < 4; ++j) {
        int i = base + t * 4 + j;
        if (i < N) s += cnt[i];
    }
    red[t] = s;
    __syncthreads();
    for (int d = 128; d > 0; d >>= 1) {
        if (t < d) red[t] += red[t + d];
        __syncthreads();
    }
    if (t == 0) bsum[blockIdx.x] = red[0];
}

// scan phase 2: exclusive scan of block partials (nb <= 1024, tiny)
__global__ void scan2_kernel(const int* __restrict__ bsum, int* __restrict__ boff, int nb) {
    __shared__ int v[1024];
    int t = threadIdx.x;
    for (int i = t; i < nb; i += 256) v[i] = bsum[i];
    __syncthreads();
    if (t == 0) {
        int run = 0;
        for (int i = 0; i < nb; ++i) { int c = v[i]; v[i] = run; run += c; }
    }
    __syncthreads();
    for (int i = t; i < nb; i += 256) boff[i] = v[i];
}

// scan phase 3: in-block scan + offset, write rowptr & pos
__global__ __launch_bounds__(256)
void scan3_kernel(const int* __restrict__ cnt, const int* __restrict__ boff,
                  int* __restrict__ rowptr, int* __restrict__ pos, int N) {
    __shared__ int wsum[4];
    int base = blockIdx.x * 1024;
    int t = threadIdx.x;
    int lane = t & 63, wv = t >> 6;
    int c[4];
    int s = 0;
#pragma unroll
    for (int j = 0; j < 4; ++j) {
        int i = base + t * 4 + j;
        c[j] = (i < N) ? cnt[i] : 0;
        s += c[j];
    }
    int val = s;
#pragma unroll
    for (int d = 1; d < 64; d <<= 1) {
        int o = __shfl_up(val, d, 64);
        if (lane >= d) val += o;
    }
    if (lane == 63) wsum[wv] = val;
    __syncthreads();
    int wadd = 0;
    for (int i = 0; i < wv; ++i) wadd += wsum[i];
    int excl = val - s + wadd + boff[blockIdx.x];
#pragma unroll
    for (int j = 0; j < 4; ++j) {
        int i = base + t * 4 + j;
        if (i < N) {
            rowptr[i] = excl;
            pos[i] = excl;
            excl += c[j];
            if (i == N - 1) rowptr[N] = excl;
        }
    }
}

__global__ __launch_bounds__(256)
void scatter_kernel(const int* __restrict__ src, const int* __restrict__ dst,
                    int* __restrict__ pos, int* __restrict__ srcs, int E) {
    int i = blockIdx.x * blockDim.x + threadIdx.x;
    if (i < E) {
        int p = atomicAdd(&pos[dst[i]], 1);
        srcs[p] = src[i];
    }
}

__global__ void bounds_kernel(const int* __restrict__ batch, int* __restrict__ start, int N) {
    int g = threadIdx.x;
    if (g > 64) return;
    int lo = 0, hi = N;
    while (lo < hi) {
        int mid = (lo + hi) >> 1;
        if (batch[mid] < g) lo = mid + 1; else hi = mid;
    }
    start[g] = lo;
}

// ---------------- conversions ----------------

__global__ __launch_bounds__(256)
void conv_x_kernel(const float* __restrict__ x, unsigned short* __restrict__ xb, int n4) {
    int i = blockIdx.x * 256 + threadIdx.x;
    if (i >= n4) return;
    float4 v = ((const float4*)x)[i];
    ush4 o = { f2b(v.x), f2b(v.y), f2b(v.z), f2b(v.w) };
    *(ush4*)(xb + (size_t)i * 4) = o;
}

// Build transposed bf16 weight buffers:
//  Wt0  [256][256]: row m, k<128 -> Wrel0[k][m], k>=128 -> Wroot0[k-128][m]
//  WtC1 [256][256]: row m<128 -> Wrel1[k][m], m>=128 -> Wroot1[k][m-128]
//  WtC2 [128][128]: row m<64  -> Wrel2[k][m], m>=64  -> Wroot2[k][m-64]
__global__ __launch_bounds__(256)
void conv_weights_kernel(const float* __restrict__ Wrel0, const float* __restrict__ Wroot0,
                         const float* __restrict__ Wrel1, const float* __restrict__ Wroot1,
                         const float* __restrict__ Wrel2, const float* __restrict__ Wroot2,
                         unsigned short* __restrict__ Wt0,
                         unsigned short* __restrict__ WtC1,
                         unsigned short* __restrict__ WtC2) {
    int i = blockIdx.x * 256 + threadIdx.x;
    if (i < 65536) {
        int m = i >> 8, k = i & 255;
        float v = (k < 128) ? Wrel0[k * 256 + m] : Wroot0[(k - 128) * 256 + m];
        Wt0[i] = f2b(v);
    } else if (i < 131072) {
        int j = i - 65536;
        int m = j >> 8, k = j & 255;
        float v = (m < 128) ? Wrel1[k * 128 + m] : Wroot1[k * 128 + (m - 128)];
        WtC1[j] = f2b(v);
    } else if (i < 147456) {
        int j = i - 131072;
        int m = j >> 7, k = j & 127;
        float v = (m < 64) ? Wrel2[k * 64 + m] : Wroot2[k * 64 + (m - 64)];
        WtC2[j] = f2b(v);
    }
}

// ---------------- aggregation over CSR (+root/bias/BN/ReLU), bf16 ----------
// One wave per node. Lane-groups process NG edges concurrently; each lane
// loads 16B (8 feats). Cross-group combine via shfl_xor butterfly.
// F=128: NG=4 groups x 16 lanes.  F=64: NG=8 groups x 8 lanes.

template<int F>
__global__ __launch_bounds__(256)
void agg_bf16(const unsigned short* __restrict__ ysrc, int ystride,
              const unsigned short* __restrict__ yroot, int rstride,
              const int* __restrict__ rowptr, const int* __restrict__ srcs,
              const float* __restrict__ bias,
              const float* __restrict__ bng, const float* __restrict__ bnb,
              const float* __restrict__ bnm, const float* __restrict__ bnv,
              unsigned short* __restrict__ out, int N)
{
    constexpr int GL = (F == 128) ? 16 : 8;   // lanes per group
    constexpr int NG = 64 / GL;               // concurrent edges
    int w = (blockIdx.x * blockDim.x + threadIdx.x) >> 6;
    int lane = threadIdx.x & 63;
    if (w >= N) return;
    int beg = rowptr[w], end = rowptr[w + 1];
    int lg = lane / GL, lr = lane % GL;

    float a[8] = {};
    int e = beg + lg;
    for (; e + NG < end; e += 2 * NG) {
        int s0 = srcs[e], s1 = srcs[e + NG];
        ush8 v0 = *(const ush8*)(ysrc + (size_t)s0 * ystride + lr * 8);
        ush8 v1 = *(const ush8*)(ysrc + (size_t)s1 * ystride + lr * 8);
#pragma unroll
        for (int j = 0; j < 8; ++j) a[j] += b2f(v0[j]) + b2f(v1[j]);
    }
    if (e < end) {
        int s0 = srcs[e];
        ush8 v0 = *(const ush8*)(ysrc + (size_t)s0 * ystride + lr * 8);
#pragma unroll
        for (int j = 0; j < 8; ++j) a[j] += b2f(v0[j]);
    }

    // combine edge-groups: butterfly over group bits
#pragma unroll
    for (int d = GL; d < 64; d <<= 1)
#pragma unroll
        for (int j = 0; j < 8; ++j)
            a[j] += __shfl_xor(a[j], d, 64);

    // epilogue on first group only (each lane owns 8 consecutive feats)
    if (lg == 0) {
        int f0 = lr * 8;
        if (yroot) {
            ush8 r = *(const ush8*)(yroot + (size_t)w * rstride + f0);
#pragma unroll
            for (int j = 0; j < 8; ++j) a[j] += b2f(r[j]);
        }
        ush8 o;
#pragma unroll
        for (int j = 0; j < 8; ++j) {
            float val = a[j];
            if (bias) {
                int f = f0 + j;
                val += bias[f];
                val = (val - bnm[f]) * rsqrtf(bnv[f] + 1e-5f) * bng[f] + bnb[f];
                val = fmaxf(val, 0.f);
            }
            o[j] = (short)f2b(val);
        }
        *(ush8*)(out + (size_t)w * F + f0) = o;
    }
}

// ---------------- bf16 MFMA GEMM: C = [epi](A @ Wt^T) -----------------------
// A: [N, Ktot] bf16 (optionally split: k<128 from A1, k>=128 from A2, each [N,128])
// Wt: [M][Ktot] bf16 (row m = output column m). C: [N, M] bf16.
// Tile: BM=128, BN=128, BK=64; 4 waves, each 64x64 (4x4 frags of 16x16x32).

__global__ __launch_bounds__(256)
void gemm_mfma(const unsigned short* __restrict__ A1,
               const unsigned short* __restrict__ A2,
               const unsigned short* __restrict__ Wt,
               const float* __restrict__ bias,
               const float* __restrict__ bng, const float* __restrict__ bnb,
               const float* __restrict__ bnm, const float* __restrict__ bnv,
               unsigned short* __restrict__ C, int N, int Ktot, int M)
{
    __shared__ unsigned short As[128][64];
    __shared__ unsigned short Ws[128][64];

    const int tid = threadIdx.x;
    const int n0 = blockIdx.x * 128;
    const int m0 = blockIdx.y * 128;
    const int wid = tid >> 6, lane = tid & 63;
    const int wm = wid >> 1, wn = wid & 1;
    const int lr = lane & 15, lg = lane >> 4;
    const int strideA = A2 ? 128 : Ktot;

    f32x4 acc[4][4] = {};

    for (int k0 = 0; k0 < Ktot; k0 += 64) {
        // stage A tile [128][64] and Wt tile [128][64]
#pragma unroll
        for (int it = 0; it < 4; ++it) {
            int c = tid + it * 256;          // 0..1023
            int row = c >> 3;
            int kb = (c & 7) << 3;           // 0..56, step 8
            int sw = kb ^ ((row & 7) << 3);
            // A
            int n = n0 + row;
            int ksrc = k0 + kb;
            const unsigned short* Ap = A1; int kl = ksrc;
            if (A2 && ksrc >= 128) { Ap = A2; kl = ksrc - 128; }
            ush8 va = {};
            if (n < N) va = *(const ush8*)(Ap + (size_t)n * strideA + kl);
            *(ush8*)&As[row][sw] = va;
            // Wt
            ush8 vw = *(const ush8*)(Wt + (size_t)(m0 + row) * Ktot + k0 + kb);
            *(ush8*)&Ws[row][sw] = vw;
        }
        __syncthreads();
#pragma unroll
        for (int s = 0; s < 2; ++s) {
            int kk = s * 32 + lg * 8;
            bf16x8 af[4], bfr[4];
#pragma unroll
            for (int i = 0; i < 4; ++i) {
                int row = wm * 64 + i * 16 + lr;
                af[i] = *(const bf16x8*)&As[row][kk ^ ((row & 7) << 3)];
            }
#pragma unroll
            for (int j = 0; j < 4; ++j) {
                int n = wn * 64 + j * 16 + lr;
                bfr[j] = *(const bf16x8*)&Ws[n][kk ^ ((n & 7) << 3)];
            }
#pragma unroll
            for (int i = 0; i < 4; ++i)
#pragma unroll
                for (int j = 0; j < 4; ++j)
                    acc[i][j] = __builtin_amdgcn_mfma_f32_16x16x32_bf16(af[i], bfr[j], acc[i][j], 0, 0, 0);
        }
        __syncthreads();
    }

    // epilogue: D row=(lg*4+r), col=lr within each 16x16 frag
#pragma unroll
    for (int i = 0; i < 4; ++i) {
#pragma unroll
        for (int r = 0; r < 4; ++r) {
            int row = n0 + wm * 64 + i * 16 + lg * 4 + r;
            if (row >= N) continue;
#pragma unroll
            for (int j = 0; j < 4; ++j) {
                int col = m0 + wn * 64 + j * 16 + lr;
                float val = acc[i][j][r];
                if (bias) {
                    val += bias[col];
                    val = (val - bnm[col]) * rsqrtf(bnv[col] + 1e-5f) * bng[col] + bnb[col];
                    val = fmaxf(val, 0.f);
                }
                C[(size_t)row * M + col] = f2b(val);
            }
        }
    }
}

// ---------------- pooling + head (bf16 h, batch sorted) ---------------------

__global__ __launch_bounds__(256)
void pool_head_kernel(const unsigned short* __restrict__ h, const int* __restrict__ start,
                      const float* __restrict__ Wout, const float* __restrict__ bout,
                      float* __restrict__ out) {
    int g = blockIdx.x;
    int f = threadIdx.x & 63, sub = threadIdx.x >> 6;
    int beg = start[g], end = start[g + 1];
    float acc = 0.f;
    for (int n = beg + sub; n < end; n += 4)
        acc += b2f(h[(size_t)n * 64 + f]);
    __shared__ float red[4][64];
    red[sub][f] = acc;
    __syncthreads();
    if (sub == 0) {
        float v = red[0][f] + red[1][f] + red[2][f] + red[3][f];
        float cnt = fmaxf((float)(end - beg), 1.0f);
        red[0][f] = v / cnt;
    }
    __syncthreads();
    if (threadIdx.x < 3) {
        int o = threadIdx.x;
        float s = 0.f;
#pragma unroll
        for (int k = 0; k < 64; ++k) s += red[0][k] * Wout[k * 3 + o];
        out[g * 3 + o] = s + bout[o];
    }
}

// ---------------- launch ----------------------------------------------------

extern "C" void kernel_launch(void* const* d_in, const int* in_sizes, int n_in,
                              void* d_out, int out_size, void* d_ws, size_t ws_size,
                              hipStream_t stream)
{
    const float* x       = (const float*)d_in[0];
    const int*   ei      = (const int*)d_in[1];
    const int*   batch   = (const int*)d_in[2];
    const float* W_rel0  = (const float*)d_in[3];
    const float* b_rel0  = (const float*)d_in[4];
    const float* W_root0 = (const float*)d_in[5];
    const float* bn_g0   = (const float*)d_in[6];
    const float* bn_b0   = (const float*)d_in[7];
    const float* bn_m0   = (const float*)d_in[8];
    const float* bn_v0   = (const float*)d_in[9];
    const float* W_rel1  = (const float*)d_in[10];
    const float* b_rel1  = (const float*)d_in[11];
    const float* W_root1 = (const float*)d_in[12];
    const float* bn_g1   = (const float*)d_in[13];
    const float* bn_b1   = (const float*)d_in[14];
    const float* bn_m1   = (const float*)d_in[15];
    const float* bn_v1   = (const float*)d_in[16];
    const float* W_rel2  = (const float*)d_in[17];
    const float* b_rel2  = (const float*)d_in[18];
    const float* W_root2 = (const float*)d_in[19];
    const float* bn_g2   = (const float*)d_in[20];
    const float* bn_b2   = (const float*)d_in[21];
    const float* bn_m2   = (const float*)d_in[22];
    const float* bn_v2   = (const float*)d_in[23];
    const float* W_out   = (const float*)d_in[24];
    const float* b_out   = (const float*)d_in[25];

    const int N = in_sizes[0] / 128;
    const int E = in_sizes[1] / 2;
    const int* src = ei;
    const int* dst = ei + E;

    char* ws = (char*)d_ws;
    size_t off = 0;
    auto alloc = [&](size_t b) -> void* {
        off = (off + 255) & ~(size_t)255;
        void* p = ws + off;
        off += b;
        return p;
    };

    unsigned short* xb16   = (unsigned short*)alloc((size_t)N * 128 * 2);
    unsigned short* aggb16 = (unsigned short*)alloc((size_t)N * 128 * 2);
    unsigned short* h0     = (unsigned short*)alloc((size_t)N * 256 * 2);
    unsigned short* ycomb1 = (unsigned short*)alloc((size_t)N * 256 * 2);
    unsigned short* h1     = (unsigned short*)alloc((size_t)N * 128 * 2);
    unsigned short* ycomb2 = (unsigned short*)alloc((size_t)N * 128 * 2);
    unsigned short* h2     = (unsigned short*)alloc((size_t)N * 64 * 2);
    unsigned short* Wt0    = (unsigned short*)alloc(256 * 256 * 2);
    unsigned short* WtC1   = (unsigned short*)alloc(256 * 256 * 2);
    unsigned short* WtC2   = (unsigned short*)alloc(128 * 128 * 2);
    int* cnt    = (int*)alloc((size_t)N * 4);
    int* rowp   = (int*)alloc((size_t)(N + 1) * 4);
    int* pos    = (int*)alloc((size_t)N * 4);
    int* srcs   = (int*)alloc((size_t)E * 4);
    int* gstart = (int*)alloc(65 * 4);
    int* bsum   = (int*)alloc(1024 * 4);
    int* boff   = (int*)alloc(1024 * 4);

    hipMemsetAsync(cnt, 0, (size_t)N * 4, stream);

    const int TB = 256;
    const int egrid = (E + TB - 1) / TB;
    const int nwb = (N + 3) / 4;
    const int nsb = (N + 1023) / 1024;   // scan blocks

    hist_kernel<<<egrid, TB, 0, stream>>>(dst, cnt, E);
    scan1_kernel<<<nsb, TB, 0, stream>>>(cnt, bsum, N);
    scan2_kernel<<<1, TB, 0, stream>>>(bsum, boff, nsb);
    scan3_kernel<<<nsb, TB, 0, stream>>>(cnt, boff, rowp, pos, N);
    scatter_kernel<<<egrid, TB, 0, stream>>>(src, dst, pos, srcs, E);
    bounds_kernel<<<1, 128, 0, stream>>>(batch, gstart, N);

    conv_weights_kernel<<<576, TB, 0, stream>>>(W_rel0, W_root0, W_rel1, W_root1,
                                                W_rel2, W_root2, Wt0, WtC1, WtC2);
    conv_x_kernel<<<(N * 128 / 4 + TB - 1) / TB, TB, 0, stream>>>(x, xb16, N * 128 / 4);

    const int gx = (N + 127) / 128;

    // layer 0: agg(x) -> [agg|x] @ Wt0 (+bias,BN,ReLU) -> h0 [N,256]
    agg_bf16<128><<<nwb, TB, 0, stream>>>(xb16, 128, nullptr, 0, rowp, srcs,
                                          nullptr, nullptr, nullptr, nullptr, nullptr,
                                          aggb16, N);
    gemm_mfma<<<dim3(gx, 2), TB, 0, stream>>>(aggb16, xb16, Wt0,
                                              b_rel0, bn_g0, bn_b0, bn_m0, bn_v0,
                                              h0, N, 256, 256);

    // layer 1: ycomb1 = h0 @ [Wrel1|Wroot1]; h1 = bnrelu(agg(yrel)+yroot+b)
    gemm_mfma<<<dim3(gx, 2), TB, 0, stream>>>(h0, nullptr, WtC1,
                                              nullptr, nullptr, nullptr, nullptr, nullptr,
                                              ycomb1, N, 256, 256);
    agg_bf16<128><<<nwb, TB, 0, stream>>>(ycomb1, 256, ycomb1 + 128, 256, rowp, srcs,
                                          b_rel1, bn_g1, bn_b1, bn_m1, bn_v1,
                                          h1, N);

    // layer 2: ycomb2 = h1 @ [Wrel2|Wroot2]; h2 = bnrelu(agg(yrel)+yroot+b)
    gemm_mfma<<<dim3(gx, 1), TB, 0, stream>>>(h1, nullptr, WtC2,
                                              nullptr, nullptr, nullptr, nullptr, nullptr,
                                              ycomb2, N, 128, 128);
    agg_bf16<64><<<nwb, TB, 0, stream>>>(ycomb2, 128, ycomb2 + 64, 128, rowp, srcs,
                                         b_rel2, bn_g2, bn_b2, bn_m2, bn_v2,
                                         h2, N);

    // mean pool + head
    pool_head_kernel<<<64, TB, 0, stream>>>(h2, gstart, W_out, b_out, (float*)d_out);
}

// Round 6
// 374.483 us; speedup vs baseline: 1.0965x; 1.0965x over previous
//
#include <hip/hip_runtime.h>

// GeneticDosageGNN: 3x GraphConv(+BN+ReLU) -> mean pool -> linear head
// N=50000 nodes, E=800000 edges, dims 128->256->128->64->3, 64 graphs.
// R6: revert gather to coalesced full-wave rows (R4 pattern), unroll-4 MLP,
//     split yrel/yroot buffers for compact gather footprint.

typedef __attribute__((ext_vector_type(8))) short    bf16x8;
typedef __attribute__((ext_vector_type(4))) float    f32x4;
typedef __attribute__((ext_vector_type(8))) unsigned short ush8;
typedef __attribute__((ext_vector_type(4))) unsigned short ush4;

__device__ __forceinline__ unsigned short f2b(float f) {
    union { float f; unsigned int u; } c; c.f = f;
    unsigned int u = c.u;
    return (unsigned short)((u + 0x7fffu + ((u >> 16) & 1u)) >> 16);
}
__device__ __forceinline__ float b2f(unsigned short h) {
    union { unsigned int u; float f; } c; c.u = ((unsigned int)h) << 16;
    return c.f;
}
__device__ __forceinline__ float blo(unsigned int u) { return b2f((unsigned short)(u & 0xffff)); }
__device__ __forceinline__ float bhi(unsigned int u) { return b2f((unsigned short)(u >> 16)); }

// ---------------- CSR build ----------------

__global__ __launch_bounds__(256)
void hist_kernel(const int* __restrict__ dst, int* __restrict__ cnt, int E) {
    int i = blockIdx.x * blockDim.x + threadIdx.x;
    if (i < E) atomicAdd(&cnt[dst[i]], 1);
}

__global__ __launch_bounds__(256)
void scan1_kernel(const int* __restrict__ cnt, int* __restrict__ bsum, int N) {
    __shared__ int red[256];
    int base = blockIdx.x * 1024;
    int t = threadIdx.x;
    int s = 0;
#pragma unroll
    for (int j = 0; j < 4; ++j) {
        int i = base + t * 4 + j;
        if (i < N) s += cnt[i];
    }
    red[t] = s;
    __syncthreads();
    for (int d = 128; d > 0; d >>= 1) {
        if (t < d) red[t] += red[t + d];
        __syncthreads();
    }
    if (t == 0) bsum[blockIdx.x] = red[0];
}

__global__ void scan2_kernel(const int* __restrict__ bsum, int* __restrict__ boff, int nb) {
    __shared__ int v[1024];
    int t = threadIdx.x;
    for (int i = t; i < nb; i += 256) v[i] = bsum[i];
    __syncthreads();
    if (t == 0) {
        int run = 0;
        for (int i = 0; i < nb; ++i) { int c = v[i]; v[i] = run; run += c; }
    }
    __syncthreads();
    for (int i = t; i < nb; i += 256) boff[i] = v[i];
}

__global__ __launch_bounds__(256)
void scan3_kernel(const int* __restrict__ cnt, const int* __restrict__ boff,
                  int* __restrict__ rowptr, int* __restrict__ pos, int N) {
    __shared__ int wsum[4];
    int base = blockIdx.x * 1024;
    int t = threadIdx.x;
    int lane = t & 63, wv = t >> 6;
    int c[4];
    int s = 0;
#pragma unroll
    for (int j = 0; j < 4; ++j) {
        int i = base + t * 4 + j;
        c[j] = (i < N) ? cnt[i] : 0;
        s += c[j];
    }
    int val = s;
#pragma unroll
    for (int d = 1; d < 64; d <<= 1) {
        int o = __shfl_up(val, d, 64);
        if (lane >= d) val += o;
    }
    if (lane == 63) wsum[wv] = val;
    __syncthreads();
    int wadd = 0;
    for (int i = 0; i < wv; ++i) wadd += wsum[i];
    int excl = val - s + wadd + boff[blockIdx.x];
#pragma unroll
    for (int j = 0; j < 4; ++j) {
        int i = base + t * 4 + j;
        if (i < N) {
            rowptr[i] = excl;
            pos[i] = excl;
            excl += c[j];
            if (i == N - 1) rowptr[N] = excl;
        }
    }
}

__global__ __launch_bounds__(256)
void scatter_kernel(const int* __restrict__ src, const int* __restrict__ dst,
                    int* __restrict__ pos, int* __restrict__ srcs, int E) {
    int i = blockIdx.x * blockDim.x + threadIdx.x;
    if (i < E) {
        int p = atomicAdd(&pos[dst[i]], 1);
        srcs[p] = src[i];
    }
}

__global__ void bounds_kernel(const int* __restrict__ batch, int* __restrict__ start, int N) {
    int g = threadIdx.x;
    if (g > 64) return;
    int lo = 0, hi = N;
    while (lo < hi) {
        int mid = (lo + hi) >> 1;
        if (batch[mid] < g) lo = mid + 1; else hi = mid;
    }
    start[g] = lo;
}

// ---------------- conversions ----------------

__global__ __launch_bounds__(256)
void conv_x_kernel(const float* __restrict__ x, unsigned short* __restrict__ xb, int n4) {
    int i = blockIdx.x * 256 + threadIdx.x;
    if (i >= n4) return;
    float4 v = ((const float4*)x)[i];
    ush4 o = { f2b(v.x), f2b(v.y), f2b(v.z), f2b(v.w) };
    *(ush4*)(xb + (size_t)i * 4) = o;
}

__global__ __launch_bounds__(256)
void conv_weights_kernel(const float* __restrict__ Wrel0, const float* __restrict__ Wroot0,
                         const float* __restrict__ Wrel1, const float* __restrict__ Wroot1,
                         const float* __restrict__ Wrel2, const float* __restrict__ Wroot2,
                         unsigned short* __restrict__ Wt0,
                         unsigned short* __restrict__ WtC1,
                         unsigned short* __restrict__ WtC2) {
    int i = blockIdx.x * 256 + threadIdx.x;
    if (i < 65536) {
        int m = i >> 8, k = i & 255;
        float v = (k < 128) ? Wrel0[k * 256 + m] : Wroot0[(k - 128) * 256 + m];
        Wt0[i] = f2b(v);
    } else if (i < 131072) {
        int j = i - 65536;
        int m = j >> 8, k = j & 255;
        float v = (m < 128) ? Wrel1[k * 128 + m] : Wroot1[k * 128 + (m - 128)];
        WtC1[j] = f2b(v);
    } else if (i < 147456) {
        int j = i - 131072;
        int m = j >> 7, k = j & 127;
        float v = (m < 64) ? Wrel2[k * 64 + m] : Wroot2[k * 64 + (m - 64)];
        WtC2[j] = f2b(v);
    }
}

// ---------------- aggregation over CSR (+root/bias/BN/ReLU), bf16 ----------
// F=128: full wave per edge (lane = 2 feats, 4B), unroll 4 -> 4 rows in flight.
// F=64:  half-wave per edge (lane = 2 feats, 4B), 2 edges/instr, unroll 2.
// Quarter-wave (16 lanes x 4B) always one contiguous 64B line.

template<int F>
__global__ __launch_bounds__(256)
void agg_bf16(const unsigned short* __restrict__ ysrc, int ystride,
              const unsigned short* __restrict__ yroot, int rstride,
              const int* __restrict__ rowptr, const int* __restrict__ srcs,
              const float* __restrict__ bias,
              const float* __restrict__ bng, const float* __restrict__ bnb,
              const float* __restrict__ bnm, const float* __restrict__ bnv,
              unsigned short* __restrict__ out, int N)
{
    int w = (blockIdx.x * blockDim.x + threadIdx.x) >> 6;
    int lane = threadIdx.x & 63;
    if (w >= N) return;
    int beg = rowptr[w], end = rowptr[w + 1];

    if (F == 128) {
        float a0 = 0.f, a1 = 0.f, b0 = 0.f, b1 = 0.f;
        float c0 = 0.f, c1 = 0.f, d0 = 0.f, d1 = 0.f;
        int e = beg;
        for (; e + 3 < end; e += 4) {
            int s0 = srcs[e], s1 = srcs[e + 1], s2 = srcs[e + 2], s3 = srcs[e + 3];
            unsigned int u0 = *(const unsigned int*)(ysrc + (size_t)s0 * ystride + lane * 2);
            unsigned int u1 = *(const unsigned int*)(ysrc + (size_t)s1 * ystride + lane * 2);
            unsigned int u2 = *(const unsigned int*)(ysrc + (size_t)s2 * ystride + lane * 2);
            unsigned int u3 = *(const unsigned int*)(ysrc + (size_t)s3 * ystride + lane * 2);
            a0 += blo(u0); a1 += bhi(u0);
            b0 += blo(u1); b1 += bhi(u1);
            c0 += blo(u2); c1 += bhi(u2);
            d0 += blo(u3); d1 += bhi(u3);
        }
        for (; e < end; ++e) {
            unsigned int u = *(const unsigned int*)(ysrc + (size_t)srcs[e] * ystride + lane * 2);
            a0 += blo(u); a1 += bhi(u);
        }
        a0 = (a0 + b0) + (c0 + d0);
        a1 = (a1 + b1) + (c1 + d1);

        int f0 = lane * 2, f1 = lane * 2 + 1;
        if (yroot) {
            unsigned int u = *(const unsigned int*)(yroot + (size_t)w * rstride + lane * 2);
            a0 += blo(u); a1 += bhi(u);
        }
        if (bias) {
            a0 += bias[f0]; a1 += bias[f1];
            a0 = (a0 - bnm[f0]) * rsqrtf(bnv[f0] + 1e-5f) * bng[f0] + bnb[f0];
            a1 = (a1 - bnm[f1]) * rsqrtf(bnv[f1] + 1e-5f) * bng[f1] + bnb[f1];
            a0 = fmaxf(a0, 0.f); a1 = fmaxf(a1, 0.f);
        }
        unsigned int o = (unsigned int)f2b(a0) | ((unsigned int)f2b(a1) << 16);
        *(unsigned int*)(out + (size_t)w * 128 + lane * 2) = o;
    } else {  // F == 64: lanes 0-31 take even-offset edges, 32-63 odd
        int half = lane >> 5;
        int lr = lane & 31;
        float a0 = 0.f, a1 = 0.f, b0 = 0.f, b1 = 0.f;
        int e = beg + half;
        for (; e + 2 < end; e += 4) {
            int s0 = srcs[e], s1 = srcs[e + 2];
            unsigned int u0 = *(const unsigned int*)(ysrc + (size_t)s0 * ystride + lr * 2);
            unsigned int u1 = *(const unsigned int*)(ysrc + (size_t)s1 * ystride + lr * 2);
            a0 += blo(u0); a1 += bhi(u0);
            b0 += blo(u1); b1 += bhi(u1);
        }
        if (e < end) {
            unsigned int u = *(const unsigned int*)(ysrc + (size_t)srcs[e] * ystride + lr * 2);
            a0 += blo(u); a1 += bhi(u);
        }
        a0 += b0; a1 += b1;
        a0 += __shfl_xor(a0, 32, 64);
        a1 += __shfl_xor(a1, 32, 64);

        if (half == 0) {
            int f0 = lr * 2, f1 = lr * 2 + 1;
            if (yroot) {
                unsigned int u = *(const unsigned int*)(yroot + (size_t)w * rstride + lr * 2);
                a0 += blo(u); a1 += bhi(u);
            }
            if (bias) {
                a0 += bias[f0]; a1 += bias[f1];
                a0 = (a0 - bnm[f0]) * rsqrtf(bnv[f0] + 1e-5f) * bng[f0] + bnb[f0];
                a1 = (a1 - bnm[f1]) * rsqrtf(bnv[f1] + 1e-5f) * bng[f1] + bnb[f1];
                a0 = fmaxf(a0, 0.f); a1 = fmaxf(a1, 0.f);
            }
            unsigned int o = (unsigned int)f2b(a0) | ((unsigned int)f2b(a1) << 16);
            *(unsigned int*)(out + (size_t)w * 64 + lr * 2) = o;
        }
    }
}

// ---------------- bf16 MFMA GEMM: C = [epi](A @ Wt^T) -----------------------
// A: [N, Ktot] bf16 (optionally split: k<128 from A1, k>=128 from A2, each [N,128])
// Wt: [M][Ktot] bf16. Output: if csplit>0, cols [0,csplit) -> C (stride csplit),
// cols [csplit,M) -> C2 (stride M-csplit); else C stride M.

__global__ __launch_bounds__(256)
void gemm_mfma(const unsigned short* __restrict__ A1,
               const unsigned short* __restrict__ A2,
               const unsigned short* __restrict__ Wt,
               const float* __restrict__ bias,
               const float* __restrict__ bng, const float* __restrict__ bnb,
               const float* __restrict__ bnm, const float* __restrict__ bnv,
               unsigned short* __restrict__ C, unsigned short* __restrict__ C2,
               int csplit, int N, int Ktot, int M)
{
    __shared__ unsigned short As[128][64];
    __shared__ unsigned short Ws[128][64];

    const int tid = threadIdx.x;
    const int n0 = blockIdx.x * 128;
    const int m0 = blockIdx.y * 128;
    const int wid = tid >> 6, lane = tid & 63;
    const int wm = wid >> 1, wn = wid & 1;
    const int lr = lane & 15, lg = lane >> 4;
    const int strideA = A2 ? 128 : Ktot;

    f32x4 acc[4][4] = {};

    for (int k0 = 0; k0 < Ktot; k0 += 64) {
#pragma unroll
        for (int it = 0; it < 4; ++it) {
            int c = tid + it * 256;
            int row = c >> 3;
            int kb = (c & 7) << 3;
            int sw = kb ^ ((row & 7) << 3);
            int n = n0 + row;
            int ksrc = k0 + kb;
            const unsigned short* Ap = A1; int kl = ksrc;
            if (A2 && ksrc >= 128) { Ap = A2; kl = ksrc - 128; }
            ush8 va = {};
            if (n < N) va = *(const ush8*)(Ap + (size_t)n * strideA + kl);
            *(ush8*)&As[row][sw] = va;
            ush8 vw = *(const ush8*)(Wt + (size_t)(m0 + row) * Ktot + k0 + kb);
            *(ush8*)&Ws[row][sw] = vw;
        }
        __syncthreads();
#pragma unroll
        for (int s = 0; s < 2; ++s) {
            int kk = s * 32 + lg * 8;
            bf16x8 af[4], bfr[4];
#pragma unroll
            for (int i = 0; i < 4; ++i) {
                int row = wm * 64 + i * 16 + lr;
                af[i] = *(const bf16x8*)&As[row][kk ^ ((row & 7) << 3)];
            }
#pragma unroll
            for (int j = 0; j < 4; ++j) {
                int n = wn * 64 + j * 16 + lr;
                bfr[j] = *(const bf16x8*)&Ws[n][kk ^ ((n & 7) << 3)];
            }
#pragma unroll
            for (int i = 0; i < 4; ++i)
#pragma unroll
                for (int j = 0; j < 4; ++j)
                    acc[i][j] = __builtin_amdgcn_mfma_f32_16x16x32_bf16(af[i], bfr[j], acc[i][j], 0, 0, 0);
        }
        __syncthreads();
    }

#pragma unroll
    for (int i = 0; i < 4; ++i) {
#pragma unroll
        for (int r = 0; r < 4; ++r) {
            int row = n0 + wm * 64 + i * 16 + lg * 4 + r;
            if (row >= N) continue;
#pragma unroll
            for (int j = 0; j < 4; ++j) {
                int col = m0 + wn * 64 + j * 16 + lr;
                float val = acc[i][j][r];
                if (bias) {
                    val += bias[col];
                    val = (val - bnm[col]) * rsqrtf(bnv[col] + 1e-5f) * bng[col] + bnb[col];
                    val = fmaxf(val, 0.f);
                }
                unsigned short* Cp;
                if (csplit > 0) {
                    if (col < csplit) Cp = C + (size_t)row * csplit + col;
                    else              Cp = C2 + (size_t)row * (M - csplit) + (col - csplit);
                } else {
                    Cp = C + (size_t)row * M + col;
                }
                *Cp = f2b(val);
            }
        }
    }
}

// ---------------- pooling + head (bf16 h, batch sorted) ---------------------

__global__ __launch_bounds__(256)
void pool_head_kernel(const unsigned short* __restrict__ h, const int* __restrict__ start,
                      const float* __restrict__ Wout, const float* __restrict__ bout,
                      float* __restrict__ out) {
    int g = blockIdx.x;
    int f = threadIdx.x & 63, sub = threadIdx.x >> 6;
    int beg = start[g], end = start[g + 1];
    float acc = 0.f;
    for (int n = beg + sub; n < end; n += 4)
        acc += b2f(h[(size_t)n * 64 + f]);
    __shared__ float red[4][64];
    red[sub][f] = acc;
    __syncthreads();
    if (sub == 0) {
        float v = red[0][f] + red[1][f] + red[2][f] + red[3][f];
        float cnt = fmaxf((float)(end - beg), 1.0f);
        red[0][f] = v / cnt;
    }
    __syncthreads();
    if (threadIdx.x < 3) {
        int o = threadIdx.x;
        float s = 0.f;
#pragma unroll
        for (int k = 0; k < 64; ++k) s += red[0][k] * Wout[k * 3 + o];
        out[g * 3 + o] = s + bout[o];
    }
}

// ---------------- launch ----------------------------------------------------

extern "C" void kernel_launch(void* const* d_in, const int* in_sizes, int n_in,
                              void* d_out, int out_size, void* d_ws, size_t ws_size,
                              hipStream_t stream)
{
    const float* x       = (const float*)d_in[0];
    const int*   ei      = (const int*)d_in[1];
    const int*   batch   = (const int*)d_in[2];
    const float* W_rel0  = (const float*)d_in[3];
    const float* b_rel0  = (const float*)d_in[4];
    const float* W_root0 = (const float*)d_in[5];
    const float* bn_g0   = (const float*)d_in[6];
    const float* bn_b0   = (const float*)d_in[7];
    const float* bn_m0   = (const float*)d_in[8];
    const float* bn_v0   = (const float*)d_in[9];
    const float* W_rel1  = (const float*)d_in[10];
    const float* b_rel1  = (const float*)d_in[11];
    const float* W_root1 = (const float*)d_in[12];
    const float* bn_g1   = (const float*)d_in[13];
    const float* bn_b1   = (const float*)d_in[14];
    const float* bn_m1   = (const float*)d_in[15];
    const float* bn_v1   = (const float*)d_in[16];
    const float* W_rel2  = (const float*)d_in[17];
    const float* b_rel2  = (const float*)d_in[18];
    const float* W_root2 = (const float*)d_in[19];
    const float* bn_g2   = (const float*)d_in[20];
    const float* bn_b2   = (const float*)d_in[21];
    const float* bn_m2   = (const float*)d_in[22];
    const float* bn_v2   = (const float*)d_in[23];
    const float* W_out   = (const float*)d_in[24];
    const float* b_out   = (const float*)d_in[25];

    const int N = in_sizes[0] / 128;
    const int E = in_sizes[1] / 2;
    const int* src = ei;
    const int* dst = ei + E;

    char* ws = (char*)d_ws;
    size_t off = 0;
    auto alloc = [&](size_t b) -> void* {
        off = (off + 255) & ~(size_t)255;
        void* p = ws + off;
        off += b;
        return p;
    };

    unsigned short* xb16   = (unsigned short*)alloc((size_t)N * 128 * 2);
    unsigned short* aggb16 = (unsigned short*)alloc((size_t)N * 128 * 2);
    unsigned short* h0     = (unsigned short*)alloc((size_t)N * 256 * 2);
    unsigned short* yrel   = (unsigned short*)alloc((size_t)N * 128 * 2);
    unsigned short* yroot  = (unsigned short*)alloc((size_t)N * 128 * 2);
    unsigned short* h1     = (unsigned short*)alloc((size_t)N * 128 * 2);
    unsigned short* h2     = (unsigned short*)alloc((size_t)N * 64 * 2);
    unsigned short* Wt0    = (unsigned short*)alloc(256 * 256 * 2);
    unsigned short* WtC1   = (unsigned short*)alloc(256 * 256 * 2);
    unsigned short* WtC2   = (unsigned short*)alloc(128 * 128 * 2);
    int* cnt    = (int*)alloc((size_t)N * 4);
    int* rowp   = (int*)alloc((size_t)(N + 1) * 4);
    int* pos    = (int*)alloc((size_t)N * 4);
    int* srcs   = (int*)alloc((size_t)E * 4);
    int* gstart = (int*)alloc(65 * 4);
    int* bsum   = (int*)alloc(1024 * 4);
    int* boff   = (int*)alloc(1024 * 4);

    hipMemsetAsync(cnt, 0, (size_t)N * 4, stream);

    const int TB = 256;
    const int egrid = (E + TB - 1) / TB;
    const int nwb = (N + 3) / 4;
    const int nsb = (N + 1023) / 1024;

    hist_kernel<<<egrid, TB, 0, stream>>>(dst, cnt, E);
    scan1_kernel<<<nsb, TB, 0, stream>>>(cnt, bsum, N);
    scan2_kernel<<<1, TB, 0, stream>>>(bsum, boff, nsb);
    scan3_kernel<<<nsb, TB, 0, stream>>>(cnt, boff, rowp, pos, N);
    scatter_kernel<<<egrid, TB, 0, stream>>>(src, dst, pos, srcs, E);
    bounds_kernel<<<1, 128, 0, stream>>>(batch, gstart, N);

    conv_weights_kernel<<<576, TB, 0, stream>>>(W_rel0, W_root0, W_rel1, W_root1,
                                                W_rel2, W_root2, Wt0, WtC1, WtC2);
    conv_x_kernel<<<(N * 128 / 4 + TB - 1) / TB, TB, 0, stream>>>(x, xb16, N * 128 / 4);

    const int gx = (N + 127) / 128;

    // layer 0: agg(x) -> [agg|x] @ Wt0 (+bias,BN,ReLU) -> h0 [N,256]
    agg_bf16<128><<<nwb, TB, 0, stream>>>(xb16, 128, nullptr, 0, rowp, srcs,
                                          nullptr, nullptr, nullptr, nullptr, nullptr,
                                          aggb16, N);
    gemm_mfma<<<dim3(gx, 2), TB, 0, stream>>>(aggb16, xb16, Wt0,
                                              b_rel0, bn_g0, bn_b0, bn_m0, bn_v0,
                                              h0, nullptr, 0, N, 256, 256);

    // layer 1: yrel/yroot = h0 @ [Wrel1|Wroot1] (split out); h1 = bnrelu(agg(yrel)+yroot+b)
    gemm_mfma<<<dim3(gx, 2), TB, 0, stream>>>(h0, nullptr, WtC1,
                                              nullptr, nullptr, nullptr, nullptr, nullptr,
                                              yrel, yroot, 128, N, 256, 256);
    agg_bf16<128><<<nwb, TB, 0, stream>>>(yrel, 128, yroot, 128, rowp, srcs,
                                          b_rel1, bn_g1, bn_b1, bn_m1, bn_v1,
                                          h1, N);

    // layer 2: yrel/yroot = h1 @ [Wrel2|Wroot2] (split out); h2 = bnrelu(agg+root+b)
    gemm_mfma<<<dim3(gx, 1), TB, 0, stream>>>(h1, nullptr, WtC2,
                                              nullptr, nullptr, nullptr, nullptr, nullptr,
                                              yrel, yroot, 64, N, 128, 128);
    agg_bf16<64><<<nwb, TB, 0, stream>>>(yrel, 64, yroot, 64, rowp, srcs,
                                         b_rel2, bn_g2, bn_b2, bn_m2, bn_v2,
                                         h2, N);

    // mean pool + head
    pool_head_kernel<<<64, TB, 0, stream>>>(h2, gstart, W_out, b_out, (float*)d_out);
}

// Round 7
// 323.005 us; speedup vs baseline: 1.2713x; 1.1594x over previous
//
#include <hip/hip_runtime.h>

// GeneticDosageGNN: 3x GraphConv(+BN+ReLU) -> mean pool -> linear head
// N=50000 nodes, E=800000 edges, dims 128->256->128->64->3, 64 graphs.
// R7: XCD-partitioned hist/scatter (kill cross-XCD line ping-pong),
//     two-phase parallel pool+head.

typedef __attribute__((ext_vector_type(8))) short    bf16x8;
typedef __attribute__((ext_vector_type(4))) float    f32x4;
typedef __attribute__((ext_vector_type(8))) unsigned short ush8;
typedef __attribute__((ext_vector_type(4))) unsigned short ush4;

__device__ __forceinline__ unsigned short f2b(float f) {
    union { float f; unsigned int u; } c; c.f = f;
    unsigned int u = c.u;
    return (unsigned short)((u + 0x7fffu + ((u >> 16) & 1u)) >> 16);
}
__device__ __forceinline__ float b2f(unsigned short h) {
    union { unsigned int u; float f; } c; c.u = ((unsigned int)h) << 16;
    return c.f;
}
__device__ __forceinline__ float blo(unsigned int u) { return b2f((unsigned short)(u & 0xffff)); }
__device__ __forceinline__ float bhi(unsigned int u) { return b2f((unsigned short)(u >> 16)); }

// ---------------- CSR build (XCD-partitioned by dst range) ----------------
// Group g = blockIdx & 7 (presumed XCD via round-robin dispatch) handles only
// dst in [g*span, (g+1)*span): every cnt/pos/srcs cache line is written by a
// single XCD -> no cross-XCD line bouncing. Correct under ANY block->XCD map.

__global__ __launch_bounds__(256)
void hist_kernel(const int* __restrict__ dst, int* __restrict__ cnt, int E, int span) {
    int grp = blockIdx.x & 7;
    int bid = blockIdx.x >> 3;
    int nb = gridDim.x >> 3;
    int lo = grp * span, hi = lo + span;
    for (int i = bid * 256 + threadIdx.x; i < E; i += nb * 256) {
        int d = dst[i];
        if (d >= lo && d < hi) atomicAdd(&cnt[d], 1);
    }
}

__global__ __launch_bounds__(256)
void scan1_kernel(const int* __restrict__ cnt, int* __restrict__ bsum, int N) {
    __shared__ int red[256];
    int base = blockIdx.x * 1024;
    int t = threadIdx.x;
    int s = 0;
#pragma unroll
    for (int j = 0; j < 4; ++j) {
        int i = base + t * 4 + j;
        if (i < N) s += cnt[i];
    }
    red[t] = s;
    __syncthreads();
    for (int d = 128; d > 0; d >>= 1) {
        if (t < d) red[t] += red[t + d];
        __syncthreads();
    }
    if (t == 0) bsum[blockIdx.x] = red[0];
}

__global__ void scan2_kernel(const int* __restrict__ bsum, int* __restrict__ boff, int nb) {
    __shared__ int v[1024];
    int t = threadIdx.x;
    for (int i = t; i < nb; i += 256) v[i] = bsum[i];
    __syncthreads();
    if (t == 0) {
        int run = 0;
        for (int i = 0; i < nb; ++i) { int c = v[i]; v[i] = run; run += c; }
    }
    __syncthreads();
    for (int i = t; i < nb; i += 256) boff[i] = v[i];
}

__global__ __launch_bounds__(256)
void scan3_kernel(const int* __restrict__ cnt, const int* __restrict__ boff,
                  int* __restrict__ rowptr, int* __restrict__ pos, int N) {
    __shared__ int wsum[4];
    int base = blockIdx.x * 1024;
    int t = threadIdx.x;
    int lane = t & 63, wv = t >> 6;
    int c[4];
    int s = 0;
#pragma unroll
    for (int j = 0; j < 4; ++j) {
        int i = base + t * 4 + j;
        c[j] = (i < N) ? cnt[i] : 0;
        s += c[j];
    }
    int val = s;
#pragma unroll
    for (int d = 1; d < 64; d <<= 1) {
        int o = __shfl_up(val, d, 64);
        if (lane >= d) val += o;
    }
    if (lane == 63) wsum[wv] = val;
    __syncthreads();
    int wadd = 0;
    for (int i = 0; i < wv; ++i) wadd += wsum[i];
    int excl = val - s + wadd + boff[blockIdx.x];
#pragma unroll
    for (int j = 0; j < 4; ++j) {
        int i = base + t * 4 + j;
        if (i < N) {
            rowptr[i] = excl;
            pos[i] = excl;
            excl += c[j];
            if (i == N - 1) rowptr[N] = excl;
        }
    }
}

__global__ __launch_bounds__(256)
void scatter_kernel(const int* __restrict__ src, const int* __restrict__ dst,
                    int* __restrict__ pos, int* __restrict__ srcs, int E, int span) {
    int grp = blockIdx.x & 7;
    int bid = blockIdx.x >> 3;
    int nb = gridDim.x >> 3;
    int lo = grp * span, hi = lo + span;
    for (int i = bid * 256 + threadIdx.x; i < E; i += nb * 256) {
        int d = dst[i];
        if (d >= lo && d < hi) {
            int p = atomicAdd(&pos[d], 1);
            srcs[p] = src[i];
        }
    }
}

__global__ void bounds_kernel(const int* __restrict__ batch, int* __restrict__ start, int N) {
    int g = threadIdx.x;
    if (g > 64) return;
    int lo = 0, hi = N;
    while (lo < hi) {
        int mid = (lo + hi) >> 1;
        if (batch[mid] < g) lo = mid + 1; else hi = mid;
    }
    start[g] = lo;
}

// ---------------- conversions ----------------

__global__ __launch_bounds__(256)
void conv_x_kernel(const float* __restrict__ x, unsigned short* __restrict__ xb, int n4) {
    int i = blockIdx.x * 256 + threadIdx.x;
    if (i >= n4) return;
    float4 v = ((const float4*)x)[i];
    ush4 o = { f2b(v.x), f2b(v.y), f2b(v.z), f2b(v.w) };
    *(ush4*)(xb + (size_t)i * 4) = o;
}

__global__ __launch_bounds__(256)
void conv_weights_kernel(const float* __restrict__ Wrel0, const float* __restrict__ Wroot0,
                         const float* __restrict__ Wrel1, const float* __restrict__ Wroot1,
                         const float* __restrict__ Wrel2, const float* __restrict__ Wroot2,
                         unsigned short* __restrict__ Wt0,
                         unsigned short* __restrict__ WtC1,
                         unsigned short* __restrict__ WtC2) {
    int i = blockIdx.x * 256 + threadIdx.x;
    if (i < 65536) {
        int m = i >> 8, k = i & 255;
        float v = (k < 128) ? Wrel0[k * 256 + m] : Wroot0[(k - 128) * 256 + m];
        Wt0[i] = f2b(v);
    } else if (i < 131072) {
        int j = i - 65536;
        int m = j >> 8, k = j & 255;
        float v = (m < 128) ? Wrel1[k * 128 + m] : Wroot1[k * 128 + (m - 128)];
        WtC1[j] = f2b(v);
    } else if (i < 147456) {
        int j = i - 131072;
        int m = j >> 7, k = j & 127;
        float v = (m < 64) ? Wrel2[k * 64 + m] : Wroot2[k * 64 + (m - 64)];
        WtC2[j] = f2b(v);
    }
}

// ---------------- aggregation over CSR (+root/bias/BN/ReLU), bf16 ----------
// F=128: full wave per edge (lane = 2 feats, 4B), unroll 4 -> 4 rows in flight.
// F=64:  half-wave per edge, 2 edges/instr, unroll 2.

template<int F>
__global__ __launch_bounds__(256)
void agg_bf16(const unsigned short* __restrict__ ysrc, int ystride,
              const unsigned short* __restrict__ yroot, int rstride,
              const int* __restrict__ rowptr, const int* __restrict__ srcs,
              const float* __restrict__ bias,
              const float* __restrict__ bng, const float* __restrict__ bnb,
              const float* __restrict__ bnm, const float* __restrict__ bnv,
              unsigned short* __restrict__ out, int N)
{
    int w = (blockIdx.x * blockDim.x + threadIdx.x) >> 6;
    int lane = threadIdx.x & 63;
    if (w >= N) return;
    int beg = rowptr[w], end = rowptr[w + 1];

    if (F == 128) {
        float a0 = 0.f, a1 = 0.f, b0 = 0.f, b1 = 0.f;
        float c0 = 0.f, c1 = 0.f, d0 = 0.f, d1 = 0.f;
        int e = beg;
        for (; e + 3 < end; e += 4) {
            int s0 = srcs[e], s1 = srcs[e + 1], s2 = srcs[e + 2], s3 = srcs[e + 3];
            unsigned int u0 = *(const unsigned int*)(ysrc + (size_t)s0 * ystride + lane * 2);
            unsigned int u1 = *(const unsigned int*)(ysrc + (size_t)s1 * ystride + lane * 2);
            unsigned int u2 = *(const unsigned int*)(ysrc + (size_t)s2 * ystride + lane * 2);
            unsigned int u3 = *(const unsigned int*)(ysrc + (size_t)s3 * ystride + lane * 2);
            a0 += blo(u0); a1 += bhi(u0);
            b0 += blo(u1); b1 += bhi(u1);
            c0 += blo(u2); c1 += bhi(u2);
            d0 += blo(u3); d1 += bhi(u3);
        }
        for (; e < end; ++e) {
            unsigned int u = *(const unsigned int*)(ysrc + (size_t)srcs[e] * ystride + lane * 2);
            a0 += blo(u); a1 += bhi(u);
        }
        a0 = (a0 + b0) + (c0 + d0);
        a1 = (a1 + b1) + (c1 + d1);

        int f0 = lane * 2, f1 = lane * 2 + 1;
        if (yroot) {
            unsigned int u = *(const unsigned int*)(yroot + (size_t)w * rstride + lane * 2);
            a0 += blo(u); a1 += bhi(u);
        }
        if (bias) {
            a0 += bias[f0]; a1 += bias[f1];
            a0 = (a0 - bnm[f0]) * rsqrtf(bnv[f0] + 1e-5f) * bng[f0] + bnb[f0];
            a1 = (a1 - bnm[f1]) * rsqrtf(bnv[f1] + 1e-5f) * bng[f1] + bnb[f1];
            a0 = fmaxf(a0, 0.f); a1 = fmaxf(a1, 0.f);
        }
        unsigned int o = (unsigned int)f2b(a0) | ((unsigned int)f2b(a1) << 16);
        *(unsigned int*)(out + (size_t)w * 128 + lane * 2) = o;
    } else {  // F == 64: lanes 0-31 take even-offset edges, 32-63 odd
        int half = lane >> 5;
        int lr = lane & 31;
        float a0 = 0.f, a1 = 0.f, b0 = 0.f, b1 = 0.f;
        int e = beg + half;
        for (; e + 2 < end; e += 4) {
            int s0 = srcs[e], s1 = srcs[e + 2];
            unsigned int u0 = *(const unsigned int*)(ysrc + (size_t)s0 * ystride + lr * 2);
            unsigned int u1 = *(const unsigned int*)(ysrc + (size_t)s1 * ystride + lr * 2);
            a0 += blo(u0); a1 += bhi(u0);
            b0 += blo(u1); b1 += bhi(u1);
        }
        if (e < end) {
            unsigned int u = *(const unsigned int*)(ysrc + (size_t)srcs[e] * ystride + lr * 2);
            a0 += blo(u); a1 += bhi(u);
        }
        a0 += b0; a1 += b1;
        a0 += __shfl_xor(a0, 32, 64);
        a1 += __shfl_xor(a1, 32, 64);

        if (half == 0) {
            int f0 = lr * 2, f1 = lr * 2 + 1;
            if (yroot) {
                unsigned int u = *(const unsigned int*)(yroot + (size_t)w * rstride + lr * 2);
                a0 += blo(u); a1 += bhi(u);
            }
            if (bias) {
                a0 += bias[f0]; a1 += bias[f1];
                a0 = (a0 - bnm[f0]) * rsqrtf(bnv[f0] + 1e-5f) * bng[f0] + bnb[f0];
                a1 = (a1 - bnm[f1]) * rsqrtf(bnv[f1] + 1e-5f) * bng[f1] + bnb[f1];
                a0 = fmaxf(a0, 0.f); a1 = fmaxf(a1, 0.f);
            }
            unsigned int o = (unsigned int)f2b(a0) | ((unsigned int)f2b(a1) << 16);
            *(unsigned int*)(out + (size_t)w * 64 + lr * 2) = o;
        }
    }
}

// ---------------- bf16 MFMA GEMM: C = [epi](A @ Wt^T) -----------------------

__global__ __launch_bounds__(256)
void gemm_mfma(const unsigned short* __restrict__ A1,
               const unsigned short* __restrict__ A2,
               const unsigned short* __restrict__ Wt,
               const float* __restrict__ bias,
               const float* __restrict__ bng, const float* __restrict__ bnb,
               const float* __restrict__ bnm, const float* __restrict__ bnv,
               unsigned short* __restrict__ C, unsigned short* __restrict__ C2,
               int csplit, int N, int Ktot, int M)
{
    __shared__ unsigned short As[128][64];
    __shared__ unsigned short Ws[128][64];

    const int tid = threadIdx.x;
    const int n0 = blockIdx.x * 128;
    const int m0 = blockIdx.y * 128;
    const int wid = tid >> 6, lane = tid & 63;
    const int wm = wid >> 1, wn = wid & 1;
    const int lr = lane & 15, lg = lane >> 4;
    const int strideA = A2 ? 128 : Ktot;

    f32x4 acc[4][4] = {};

    for (int k0 = 0; k0 < Ktot; k0 += 64) {
#pragma unroll
        for (int it = 0; it < 4; ++it) {
            int c = tid + it * 256;
            int row = c >> 3;
            int kb = (c & 7) << 3;
            int sw = kb ^ ((row & 7) << 3);
            int n = n0 + row;
            int ksrc = k0 + kb;
            const unsigned short* Ap = A1; int kl = ksrc;
            if (A2 && ksrc >= 128) { Ap = A2; kl = ksrc - 128; }
            ush8 va = {};
            if (n < N) va = *(const ush8*)(Ap + (size_t)n * strideA + kl);
            *(ush8*)&As[row][sw] = va;
            ush8 vw = *(const ush8*)(Wt + (size_t)(m0 + row) * Ktot + k0 + kb);
            *(ush8*)&Ws[row][sw] = vw;
        }
        __syncthreads();
#pragma unroll
        for (int s = 0; s < 2; ++s) {
            int kk = s * 32 + lg * 8;
            bf16x8 af[4], bfr[4];
#pragma unroll
            for (int i = 0; i < 4; ++i) {
                int row = wm * 64 + i * 16 + lr;
                af[i] = *(const bf16x8*)&As[row][kk ^ ((row & 7) << 3)];
            }
#pragma unroll
            for (int j = 0; j < 4; ++j) {
                int n = wn * 64 + j * 16 + lr;
                bfr[j] = *(const bf16x8*)&Ws[n][kk ^ ((n & 7) << 3)];
            }
#pragma unroll
            for (int i = 0; i < 4; ++i)
#pragma unroll
                for (int j = 0; j < 4; ++j)
                    acc[i][j] = __builtin_amdgcn_mfma_f32_16x16x32_bf16(af[i], bfr[j], acc[i][j], 0, 0, 0);
        }
        __syncthreads();
    }

#pragma unroll
    for (int i = 0; i < 4; ++i) {
#pragma unroll
        for (int r = 0; r < 4; ++r) {
            int row = n0 + wm * 64 + i * 16 + lg * 4 + r;
            if (row >= N) continue;
#pragma unroll
            for (int j = 0; j < 4; ++j) {
                int col = m0 + wn * 64 + j * 16 + lr;
                float val = acc[i][j][r];
                if (bias) {
                    val += bias[col];
                    val = (val - bnm[col]) * rsqrtf(bnv[col] + 1e-5f) * bng[col] + bnb[col];
                    val = fmaxf(val, 0.f);
                }
                unsigned short* Cp;
                if (csplit > 0) {
                    if (col < csplit) Cp = C + (size_t)row * csplit + col;
                    else              Cp = C2 + (size_t)row * (M - csplit) + (col - csplit);
                } else {
                    Cp = C + (size_t)row * M + col;
                }
                *Cp = f2b(val);
            }
        }
    }
}

// ---------------- pooling + head (two-phase, batch sorted) ------------------

__global__ __launch_bounds__(256)
void pool_part_kernel(const unsigned short* __restrict__ h, const int* __restrict__ start,
                      float* __restrict__ partial) {
    int g = blockIdx.x >> 3, c = blockIdx.x & 7;
    int f = threadIdx.x & 63, sub = threadIdx.x >> 6;
    int beg = start[g], end = start[g + 1];
    int cnt = end - beg;
    int cbeg = beg + (int)(((long long)cnt * c) >> 3);
    int cend = beg + (int)(((long long)cnt * (c + 1)) >> 3);
    float acc = 0.f;
    for (int n = cbeg + sub; n < cend; n += 4)
        acc += b2f(h[(size_t)n * 64 + f]);
    __shared__ float red[4][64];
    red[sub][f] = acc;
    __syncthreads();
    if (sub == 0)
        partial[(size_t)blockIdx.x * 64 + f] = red[0][f] + red[1][f] + red[2][f] + red[3][f];
}

__global__ void head_final_kernel(const float* __restrict__ partial, const int* __restrict__ start,
                                  const float* __restrict__ Wout, const float* __restrict__ bout,
                                  float* __restrict__ out) {
    int g = blockIdx.x;
    int f = threadIdx.x;
    float s = 0.f;
#pragma unroll
    for (int c = 0; c < 8; ++c) s += partial[(size_t)(g * 8 + c) * 64 + f];
    float cnt = fmaxf((float)(start[g + 1] - start[g]), 1.0f);
    __shared__ float red[64];
    red[f] = s / cnt;
    __syncthreads();
    if (f < 3) {
        float acc = 0.f;
#pragma unroll
        for (int k = 0; k < 64; ++k) acc += red[k] * Wout[k * 3 + f];
        out[g * 3 + f] = acc + bout[f];
    }
}

// ---------------- launch ----------------------------------------------------

extern "C" void kernel_launch(void* const* d_in, const int* in_sizes, int n_in,
                              void* d_out, int out_size, void* d_ws, size_t ws_size,
                              hipStream_t stream)
{
    const float* x       = (const float*)d_in[0];
    const int*   ei      = (const int*)d_in[1];
    const int*   batch   = (const int*)d_in[2];
    const float* W_rel0  = (const float*)d_in[3];
    const float* b_rel0  = (const float*)d_in[4];
    const float* W_root0 = (const float*)d_in[5];
    const float* bn_g0   = (const float*)d_in[6];
    const float* bn_b0   = (const float*)d_in[7];
    const float* bn_m0   = (const float*)d_in[8];
    const float* bn_v0   = (const float*)d_in[9];
    const float* W_rel1  = (const float*)d_in[10];
    const float* b_rel1  = (const float*)d_in[11];
    const float* W_root1 = (const float*)d_in[12];
    const float* bn_g1   = (const float*)d_in[13];
    const float* bn_b1   = (const float*)d_in[14];
    const float* bn_m1   = (const float*)d_in[15];
    const float* bn_v1   = (const float*)d_in[16];
    const float* W_rel2  = (const float*)d_in[17];
    const float* b_rel2  = (const float*)d_in[18];
    const float* W_root2 = (const float*)d_in[19];
    const float* bn_g2   = (const float*)d_in[20];
    const float* bn_b2   = (const float*)d_in[21];
    const float* bn_m2   = (const float*)d_in[22];
    const float* bn_v2   = (const float*)d_in[23];
    const float* W_out   = (const float*)d_in[24];
    const float* b_out   = (const float*)d_in[25];

    const int N = in_sizes[0] / 128;
    const int E = in_sizes[1] / 2;
    const int* src = ei;
    const int* dst = ei + E;

    char* ws = (char*)d_ws;
    size_t off = 0;
    auto alloc = [&](size_t b) -> void* {
        off = (off + 255) & ~(size_t)255;
        void* p = ws + off;
        off += b;
        return p;
    };

    unsigned short* xb16   = (unsigned short*)alloc((size_t)N * 128 * 2);
    unsigned short* aggb16 = (unsigned short*)alloc((size_t)N * 128 * 2);
    unsigned short* h0     = (unsigned short*)alloc((size_t)N * 256 * 2);
    unsigned short* yrel   = (unsigned short*)alloc((size_t)N * 128 * 2);
    unsigned short* yroot  = (unsigned short*)alloc((size_t)N * 128 * 2);
    unsigned short* h1     = (unsigned short*)alloc((size_t)N * 128 * 2);
    unsigned short* h2     = (unsigned short*)alloc((size_t)N * 64 * 2);
    unsigned short* Wt0    = (unsigned short*)alloc(256 * 256 * 2);
    unsigned short* WtC1   = (unsigned short*)alloc(256 * 256 * 2);
    unsigned short* WtC2   = (unsigned short*)alloc(128 * 128 * 2);
    int* cnt    = (int*)alloc((size_t)N * 4);
    int* rowp   = (int*)alloc((size_t)(N + 1) * 4);
    int* pos    = (int*)alloc((size_t)N * 4);
    int* srcs   = (int*)alloc((size_t)E * 4);
    int* gstart = (int*)alloc(65 * 4);
    int* bsum   = (int*)alloc(1024 * 4);
    int* boff   = (int*)alloc(1024 * 4);
    float* partial = (float*)alloc((size_t)512 * 64 * 4);

    hipMemsetAsync(cnt, 0, (size_t)N * 4, stream);

    const int TB = 256;
    const int nwb = (N + 3) / 4;
    const int nsb = (N + 1023) / 1024;
    const int span = (N + 7) / 8;

    hist_kernel<<<1024, TB, 0, stream>>>(dst, cnt, E, span);
    scan1_kernel<<<nsb, TB, 0, stream>>>(cnt, bsum, N);
    scan2_kernel<<<1, TB, 0, stream>>>(bsum, boff, nsb);
    scan3_kernel<<<nsb, TB, 0, stream>>>(cnt, boff, rowp, pos, N);
    scatter_kernel<<<1024, TB, 0, stream>>>(src, dst, pos, srcs, E, span);
    bounds_kernel<<<1, 128, 0, stream>>>(batch, gstart, N);

    conv_weights_kernel<<<576, TB, 0, stream>>>(W_rel0, W_root0, W_rel1, W_root1,
                                                W_rel2, W_root2, Wt0, WtC1, WtC2);
    conv_x_kernel<<<(N * 128 / 4 + TB - 1) / TB, TB, 0, stream>>>(x, xb16, N * 128 / 4);

    const int gx = (N + 127) / 128;

    // layer 0: agg(x) -> [agg|x] @ Wt0 (+bias,BN,ReLU) -> h0 [N,256]
    agg_bf16<128><<<nwb, TB, 0, stream>>>(xb16, 128, nullptr, 0, rowp, srcs,
                                          nullptr, nullptr, nullptr, nullptr, nullptr,
                                          aggb16, N);
    gemm_mfma<<<dim3(gx, 2), TB, 0, stream>>>(aggb16, xb16, Wt0,
                                              b_rel0, bn_g0, bn_b0, bn_m0, bn_v0,
                                              h0, nullptr, 0, N, 256, 256);

    // layer 1: yrel/yroot = h0 @ [Wrel1|Wroot1]; h1 = bnrelu(agg(yrel)+yroot+b)
    gemm_mfma<<<dim3(gx, 2), TB, 0, stream>>>(h0, nullptr, WtC1,
                                              nullptr, nullptr, nullptr, nullptr, nullptr,
                                              yrel, yroot, 128, N, 256, 256);
    agg_bf16<128><<<nwb, TB, 0, stream>>>(yrel, 128, yroot, 128, rowp, srcs,
                                          b_rel1, bn_g1, bn_b1, bn_m1, bn_v1,
                                          h1, N);

    // layer 2: yrel/yroot = h1 @ [Wrel2|Wroot2]; h2 = bnrelu(agg+root+b)
    gemm_mfma<<<dim3(gx, 1), TB, 0, stream>>>(h1, nullptr, WtC2,
                                              nullptr, nullptr, nullptr, nullptr, nullptr,
                                              yrel, yroot, 64, N, 128, 128);
    agg_bf16<64><<<nwb, TB, 0, stream>>>(yrel, 64, yroot, 64, rowp, srcs,
                                         b_rel2, bn_g2, bn_b2, bn_m2, bn_v2,
                                         h2, N);

    // mean pool + head (two-phase)
    pool_part_kernel<<<512, TB, 0, stream>>>(h2, gstart, partial);
    head_final_kernel<<<64, 64, 0, stream>>>(partial, gstart, W_out, b_out, (float*)d_out);
}

// Round 8
// 291.428 us; speedup vs baseline: 1.4090x; 1.1084x over previous
//
#include <hip/hip_runtime.h>

// GeneticDosageGNN: 3x GraphConv(+BN+ReLU) -> mean pool -> linear head
// N=50000 nodes, E=800000 edges, dims 128->256->128->64->3, 64 graphs.
// R8: GEMM tile 64x128 (was 128x128) -> 2x blocks, 24KB LDS, ~4 blocks/CU
//     to hide HBM latency in the memory-bound regime.

typedef __attribute__((ext_vector_type(8))) short    bf16x8;
typedef __attribute__((ext_vector_type(4))) float    f32x4;
typedef __attribute__((ext_vector_type(8))) unsigned short ush8;
typedef __attribute__((ext_vector_type(4))) unsigned short ush4;

__device__ __forceinline__ unsigned short f2b(float f) {
    union { float f; unsigned int u; } c; c.f = f;
    unsigned int u = c.u;
    return (unsigned short)((u + 0x7fffu + ((u >> 16) & 1u)) >> 16);
}
__device__ __forceinline__ float b2f(unsigned short h) {
    union { unsigned int u; float f; } c; c.u = ((unsigned int)h) << 16;
    return c.f;
}
__device__ __forceinline__ float blo(unsigned int u) { return b2f((unsigned short)(u & 0xffff)); }
__device__ __forceinline__ float bhi(unsigned int u) { return b2f((unsigned short)(u >> 16)); }

// ---------------- CSR build (XCD-partitioned by dst range) ----------------

__global__ __launch_bounds__(256)
void hist_kernel(const int* __restrict__ dst, int* __restrict__ cnt, int E, int span) {
    int grp = blockIdx.x & 7;
    int bid = blockIdx.x >> 3;
    int nb = gridDim.x >> 3;
    int lo = grp * span, hi = lo + span;
    for (int i = bid * 256 + threadIdx.x; i < E; i += nb * 256) {
        int d = dst[i];
        if (d >= lo && d < hi) atomicAdd(&cnt[d], 1);
    }
}

__global__ __launch_bounds__(256)
void scan1_kernel(const int* __restrict__ cnt, int* __restrict__ bsum, int N) {
    __shared__ int red[256];
    int base = blockIdx.x * 1024;
    int t = threadIdx.x;
    int s = 0;
#pragma unroll
    for (int j = 0; j < 4; ++j) {
        int i = base + t * 4 + j;
        if (i < N) s += cnt[i];
    }
    red[t] = s;
    __syncthreads();
    for (int d = 128; d > 0; d >>= 1) {
        if (t < d) red[t] += red[t + d];
        __syncthreads();
    }
    if (t == 0) bsum[blockIdx.x] = red[0];
}

__global__ void scan2_kernel(const int* __restrict__ bsum, int* __restrict__ boff, int nb) {
    __shared__ int v[1024];
    int t = threadIdx.x;
    for (int i = t; i < nb; i += 256) v[i] = bsum[i];
    __syncthreads();
    if (t == 0) {
        int run = 0;
        for (int i = 0; i < nb; ++i) { int c = v[i]; v[i] = run; run += c; }
    }
    __syncthreads();
    for (int i = t; i < nb; i += 256) boff[i] = v[i];
}

__global__ __launch_bounds__(256)
void scan3_kernel(const int* __restrict__ cnt, const int* __restrict__ boff,
                  int* __restrict__ rowptr, int* __restrict__ pos, int N) {
    __shared__ int wsum[4];
    int base = blockIdx.x * 1024;
    int t = threadIdx.x;
    int lane = t & 63, wv = t >> 6;
    int c[4];
    int s = 0;
#pragma unroll
    for (int j = 0; j < 4; ++j) {
        int i = base + t * 4 + j;
        c[j] = (i < N) ? cnt[i] : 0;
        s += c[j];
    }
    int val = s;
#pragma unroll
    for (int d = 1; d < 64; d <<= 1) {
        int o = __shfl_up(val, d, 64);
        if (lane >= d) val += o;
    }
    if (lane == 63) wsum[wv] = val;
    __syncthreads();
    int wadd = 0;
    for (int i = 0; i < wv; ++i) wadd += wsum[i];
    int excl = val - s + wadd + boff[blockIdx.x];
#pragma unroll
    for (int j = 0; j < 4; ++j) {
        int i = base + t * 4 + j;
        if (i < N) {
            rowptr[i] = excl;
            pos[i] = excl;
            excl += c[j];
            if (i == N - 1) rowptr[N] = excl;
        }
    }
}

__global__ __launch_bounds__(256)
void scatter_kernel(const int* __restrict__ src, const int* __restrict__ dst,
                    int* __restrict__ pos, int* __restrict__ srcs, int E, int span) {
    int grp = blockIdx.x & 7;
    int bid = blockIdx.x >> 3;
    int nb = gridDim.x >> 3;
    int lo = grp * span, hi = lo + span;
    for (int i = bid * 256 + threadIdx.x; i < E; i += nb * 256) {
        int d = dst[i];
        if (d >= lo && d < hi) {
            int p = atomicAdd(&pos[d], 1);
            srcs[p] = src[i];
        }
    }
}

__global__ void bounds_kernel(const int* __restrict__ batch, int* __restrict__ start, int N) {
    int g = threadIdx.x;
    if (g > 64) return;
    int lo = 0, hi = N;
    while (lo < hi) {
        int mid = (lo + hi) >> 1;
        if (batch[mid] < g) lo = mid + 1; else hi = mid;
    }
    start[g] = lo;
}

// ---------------- conversions ----------------

__global__ __launch_bounds__(256)
void conv_x_kernel(const float* __restrict__ x, unsigned short* __restrict__ xb, int n4) {
    int i = blockIdx.x * 256 + threadIdx.x;
    if (i >= n4) return;
    float4 v = ((const float4*)x)[i];
    ush4 o = { f2b(v.x), f2b(v.y), f2b(v.z), f2b(v.w) };
    *(ush4*)(xb + (size_t)i * 4) = o;
}

__global__ __launch_bounds__(256)
void conv_weights_kernel(const float* __restrict__ Wrel0, const float* __restrict__ Wroot0,
                         const float* __restrict__ Wrel1, const float* __restrict__ Wroot1,
                         const float* __restrict__ Wrel2, const float* __restrict__ Wroot2,
                         unsigned short* __restrict__ Wt0,
                         unsigned short* __restrict__ WtC1,
                         unsigned short* __restrict__ WtC2) {
    int i = blockIdx.x * 256 + threadIdx.x;
    if (i < 65536) {
        int m = i >> 8, k = i & 255;
        float v = (k < 128) ? Wrel0[k * 256 + m] : Wroot0[(k - 128) * 256 + m];
        Wt0[i] = f2b(v);
    } else if (i < 131072) {
        int j = i - 65536;
        int m = j >> 8, k = j & 255;
        float v = (m < 128) ? Wrel1[k * 128 + m] : Wroot1[k * 128 + (m - 128)];
        WtC1[j] = f2b(v);
    } else if (i < 147456) {
        int j = i - 131072;
        int m = j >> 7, k = j & 127;
        float v = (m < 64) ? Wrel2[k * 64 + m] : Wroot2[k * 64 + (m - 64)];
        WtC2[j] = f2b(v);
    }
}

// ---------------- aggregation over CSR (+root/bias/BN/ReLU), bf16 ----------

template<int F>
__global__ __launch_bounds__(256)
void agg_bf16(const unsigned short* __restrict__ ysrc, int ystride,
              const unsigned short* __restrict__ yroot, int rstride,
              const int* __restrict__ rowptr, const int* __restrict__ srcs,
              const float* __restrict__ bias,
              const float* __restrict__ bng, const float* __restrict__ bnb,
              const float* __restrict__ bnm, const float* __restrict__ bnv,
              unsigned short* __restrict__ out, int N)
{
    int w = (blockIdx.x * blockDim.x + threadIdx.x) >> 6;
    int lane = threadIdx.x & 63;
    if (w >= N) return;
    int beg = rowptr[w], end = rowptr[w + 1];

    if (F == 128) {
        float a0 = 0.f, a1 = 0.f, b0 = 0.f, b1 = 0.f;
        float c0 = 0.f, c1 = 0.f, d0 = 0.f, d1 = 0.f;
        int e = beg;
        for (; e + 3 < end; e += 4) {
            int s0 = srcs[e], s1 = srcs[e + 1], s2 = srcs[e + 2], s3 = srcs[e + 3];
            unsigned int u0 = *(const unsigned int*)(ysrc + (size_t)s0 * ystride + lane * 2);
            unsigned int u1 = *(const unsigned int*)(ysrc + (size_t)s1 * ystride + lane * 2);
            unsigned int u2 = *(const unsigned int*)(ysrc + (size_t)s2 * ystride + lane * 2);
            unsigned int u3 = *(const unsigned int*)(ysrc + (size_t)s3 * ystride + lane * 2);
            a0 += blo(u0); a1 += bhi(u0);
            b0 += blo(u1); b1 += bhi(u1);
            c0 += blo(u2); c1 += bhi(u2);
            d0 += blo(u3); d1 += bhi(u3);
        }
        for (; e < end; ++e) {
            unsigned int u = *(const unsigned int*)(ysrc + (size_t)srcs[e] * ystride + lane * 2);
            a0 += blo(u); a1 += bhi(u);
        }
        a0 = (a0 + b0) + (c0 + d0);
        a1 = (a1 + b1) + (c1 + d1);

        int f0 = lane * 2, f1 = lane * 2 + 1;
        if (yroot) {
            unsigned int u = *(const unsigned int*)(yroot + (size_t)w * rstride + lane * 2);
            a0 += blo(u); a1 += bhi(u);
        }
        if (bias) {
            a0 += bias[f0]; a1 += bias[f1];
            a0 = (a0 - bnm[f0]) * rsqrtf(bnv[f0] + 1e-5f) * bng[f0] + bnb[f0];
            a1 = (a1 - bnm[f1]) * rsqrtf(bnv[f1] + 1e-5f) * bng[f1] + bnb[f1];
            a0 = fmaxf(a0, 0.f); a1 = fmaxf(a1, 0.f);
        }
        unsigned int o = (unsigned int)f2b(a0) | ((unsigned int)f2b(a1) << 16);
        *(unsigned int*)(out + (size_t)w * 128 + lane * 2) = o;
    } else {  // F == 64: lanes 0-31 take even-offset edges, 32-63 odd
        int half = lane >> 5;
        int lr = lane & 31;
        float a0 = 0.f, a1 = 0.f, b0 = 0.f, b1 = 0.f;
        int e = beg + half;
        for (; e + 2 < end; e += 4) {
            int s0 = srcs[e], s1 = srcs[e + 2];
            unsigned int u0 = *(const unsigned int*)(ysrc + (size_t)s0 * ystride + lr * 2);
            unsigned int u1 = *(const unsigned int*)(ysrc + (size_t)s1 * ystride + lr * 2);
            a0 += blo(u0); a1 += bhi(u0);
            b0 += blo(u1); b1 += bhi(u1);
        }
        if (e < end) {
            unsigned int u = *(const unsigned int*)(ysrc + (size_t)srcs[e] * ystride + lr * 2);
            a0 += blo(u); a1 += bhi(u);
        }
        a0 += b0; a1 += b1;
        a0 += __shfl_xor(a0, 32, 64);
        a1 += __shfl_xor(a1, 32, 64);

        if (half == 0) {
            int f0 = lr * 2, f1 = lr * 2 + 1;
            if (yroot) {
                unsigned int u = *(const unsigned int*)(yroot + (size_t)w * rstride + lr * 2);
                a0 += blo(u); a1 += bhi(u);
            }
            if (bias) {
                a0 += bias[f0]; a1 += bias[f1];
                a0 = (a0 - bnm[f0]) * rsqrtf(bnv[f0] + 1e-5f) * bng[f0] + bnb[f0];
                a1 = (a1 - bnm[f1]) * rsqrtf(bnv[f1] + 1e-5f) * bng[f1] + bnb[f1];
                a0 = fmaxf(a0, 0.f); a1 = fmaxf(a1, 0.f);
            }
            unsigned int o = (unsigned int)f2b(a0) | ((unsigned int)f2b(a1) << 16);
            *(unsigned int*)(out + (size_t)w * 64 + lr * 2) = o;
        }
    }
}

// ---------------- bf16 MFMA GEMM: C = [epi](A @ Wt^T) -----------------------
// Tile BM=64, BN=128, BK=64; 4 waves, each 32x64 (2x4 frags). 24KB LDS.

__global__ __launch_bounds__(256)
void gemm_mfma(const unsigned short* __restrict__ A1,
               const unsigned short* __restrict__ A2,
               const unsigned short* __restrict__ Wt,
               const float* __restrict__ bias,
               const float* __restrict__ bng, const float* __restrict__ bnb,
               const float* __restrict__ bnm, const float* __restrict__ bnv,
               unsigned short* __restrict__ C, unsigned short* __restrict__ C2,
               int csplit, int N, int Ktot, int M)
{
    __shared__ unsigned short As[64][64];
    __shared__ unsigned short Ws[128][64];

    const int tid = threadIdx.x;
    const int n0 = blockIdx.x * 64;
    const int m0 = blockIdx.y * 128;
    const int wid = tid >> 6, lane = tid & 63;
    const int wm = wid >> 1, wn = wid & 1;      // 2x2 waves over 32-row x 64-col
    const int lr = lane & 15, lg = lane >> 4;
    const int strideA = A2 ? 128 : Ktot;

    f32x4 acc[2][4] = {};

    for (int k0 = 0; k0 < Ktot; k0 += 64) {
        // stage A tile [64][64]: 512 ush8 slots, 2 per thread
#pragma unroll
        for (int it = 0; it < 2; ++it) {
            int c = tid + it * 256;
            int row = c >> 3;
            int kb = (c & 7) << 3;
            int sw = kb ^ ((row & 7) << 3);
            int n = n0 + row;
            int ksrc = k0 + kb;
            const unsigned short* Ap = A1; int kl = ksrc;
            if (A2 && ksrc >= 128) { Ap = A2; kl = ksrc - 128; }
            ush8 va = {};
            if (n < N) va = *(const ush8*)(Ap + (size_t)n * strideA + kl);
            *(ush8*)&As[row][sw] = va;
        }
        // stage W tile [128][64]: 1024 slots, 4 per thread
#pragma unroll
        for (int it = 0; it < 4; ++it) {
            int c = tid + it * 256;
            int row = c >> 3;
            int kb = (c & 7) << 3;
            int sw = kb ^ ((row & 7) << 3);
            ush8 vw = *(const ush8*)(Wt + (size_t)(m0 + row) * Ktot + k0 + kb);
            *(ush8*)&Ws[row][sw] = vw;
        }
        __syncthreads();
#pragma unroll
        for (int s = 0; s < 2; ++s) {
            int kk = s * 32 + lg * 8;
            bf16x8 af[2], bfr[4];
#pragma unroll
            for (int i = 0; i < 2; ++i) {
                int row = wm * 32 + i * 16 + lr;
                af[i] = *(const bf16x8*)&As[row][kk ^ ((row & 7) << 3)];
            }
#pragma unroll
            for (int j = 0; j < 4; ++j) {
                int wr = wn * 64 + j * 16 + lr;
                bfr[j] = *(const bf16x8*)&Ws[wr][kk ^ ((wr & 7) << 3)];
            }
#pragma unroll
            for (int i = 0; i < 2; ++i)
#pragma unroll
                for (int j = 0; j < 4; ++j)
                    acc[i][j] = __builtin_amdgcn_mfma_f32_16x16x32_bf16(af[i], bfr[j], acc[i][j], 0, 0, 0);
        }
        __syncthreads();
    }

#pragma unroll
    for (int i = 0; i < 2; ++i) {
#pragma unroll
        for (int r = 0; r < 4; ++r) {
            int row = n0 + wm * 32 + i * 16 + lg * 4 + r;
            if (row >= N) continue;
#pragma unroll
            for (int j = 0; j < 4; ++j) {
                int col = m0 + wn * 64 + j * 16 + lr;
                float val = acc[i][j][r];
                if (bias) {
                    val += bias[col];
                    val = (val - bnm[col]) * rsqrtf(bnv[col] + 1e-5f) * bng[col] + bnb[col];
                    val = fmaxf(val, 0.f);
                }
                unsigned short* Cp;
                if (csplit > 0) {
                    if (col < csplit) Cp = C + (size_t)row * csplit + col;
                    else              Cp = C2 + (size_t)row * (M - csplit) + (col - csplit);
                } else {
                    Cp = C + (size_t)row * M + col;
                }
                *Cp = f2b(val);
            }
        }
    }
}

// ---------------- pooling + head (two-phase, batch sorted) ------------------

__global__ __launch_bounds__(256)
void pool_part_kernel(const unsigned short* __restrict__ h, const int* __restrict__ start,
                      float* __restrict__ partial) {
    int g = blockIdx.x >> 3, c = blockIdx.x & 7;
    int f = threadIdx.x & 63, sub = threadIdx.x >> 6;
    int beg = start[g], end = start[g + 1];
    int cnt = end - beg;
    int cbeg = beg + (int)(((long long)cnt * c) >> 3);
    int cend = beg + (int)(((long long)cnt * (c + 1)) >> 3);
    float acc = 0.f;
    for (int n = cbeg + sub; n < cend; n += 4)
        acc += b2f(h[(size_t)n * 64 + f]);
    __shared__ float red[4][64];
    red[sub][f] = acc;
    __syncthreads();
    if (sub == 0)
        partial[(size_t)blockIdx.x * 64 + f] = red[0][f] + red[1][f] + red[2][f] + red[3][f];
}

__global__ void head_final_kernel(const float* __restrict__ partial, const int* __restrict__ start,
                                  const float* __restrict__ Wout, const float* __restrict__ bout,
                                  float* __restrict__ out) {
    int g = blockIdx.x;
    int f = threadIdx.x;
    float s = 0.f;
#pragma unroll
    for (int c = 0; c < 8; ++c) s += partial[(size_t)(g * 8 + c) * 64 + f];
    float cnt = fmaxf((float)(start[g + 1] - start[g]), 1.0f);
    __shared__ float red[64];
    red[f] = s / cnt;
    __syncthreads();
    if (f < 3) {
        float acc = 0.f;
#pragma unroll
        for (int k = 0; k < 64; ++k) acc += red[k] * Wout[k * 3 + f];
        out[g * 3 + f] = acc + bout[f];
    }
}

// ---------------- launch ----------------------------------------------------

extern "C" void kernel_launch(void* const* d_in, const int* in_sizes, int n_in,
                              void* d_out, int out_size, void* d_ws, size_t ws_size,
                              hipStream_t stream)
{
    const float* x       = (const float*)d_in[0];
    const int*   ei      = (const int*)d_in[1];
    const int*   batch   = (const int*)d_in[2];
    const float* W_rel0  = (const float*)d_in[3];
    const float* b_rel0  = (const float*)d_in[4];
    const float* W_root0 = (const float*)d_in[5];
    const float* bn_g0   = (const float*)d_in[6];
    const float* bn_b0   = (const float*)d_in[7];
    const float* bn_m0   = (const float*)d_in[8];
    const float* bn_v0   = (const float*)d_in[9];
    const float* W_rel1  = (const float*)d_in[10];
    const float* b_rel1  = (const float*)d_in[11];
    const float* W_root1 = (const float*)d_in[12];
    const float* bn_g1   = (const float*)d_in[13];
    const float* bn_b1   = (const float*)d_in[14];
    const float* bn_m1   = (const float*)d_in[15];
    const float* bn_v1   = (const float*)d_in[16];
    const float* W_rel2  = (const float*)d_in[17];
    const float* b_rel2  = (const float*)d_in[18];
    const float* W_root2 = (const float*)d_in[19];
    const float* bn_g2   = (const float*)d_in[20];
    const float* bn_b2   = (const float*)d_in[21];
    const float* bn_m2   = (const float*)d_in[22];
    const float* bn_v2   = (const float*)d_in[23];
    const float* W_out   = (const float*)d_in[24];
    const float* b_out   = (const float*)d_in[25];

    const int N = in_sizes[0] / 128;
    const int E = in_sizes[1] / 2;
    const int* src = ei;
    const int* dst = ei + E;

    char* ws = (char*)d_ws;
    size_t off = 0;
    auto alloc = [&](size_t b) -> void* {
        off = (off + 255) & ~(size_t)255;
        void* p = ws + off;
        off += b;
        return p;
    };

    unsigned short* xb16   = (unsigned short*)alloc((size_t)N * 128 * 2);
    unsigned short* aggb16 = (unsigned short*)alloc((size_t)N * 128 * 2);
    unsigned short* h0     = (unsigned short*)alloc((size_t)N * 256 * 2);
    unsigned short* yrel   = (unsigned short*)alloc((size_t)N * 128 * 2);
    unsigned short* yroot  = (unsigned short*)alloc((size_t)N * 128 * 2);
    unsigned short* h1     = (unsigned short*)alloc((size_t)N * 128 * 2);
    unsigned short* h2     = (unsigned short*)alloc((size_t)N * 64 * 2);
    unsigned short* Wt0    = (unsigned short*)alloc(256 * 256 * 2);
    unsigned short* WtC1   = (unsigned short*)alloc(256 * 256 * 2);
    unsigned short* WtC2   = (unsigned short*)alloc(128 * 128 * 2);
    int* cnt    = (int*)alloc((size_t)N * 4);
    int* rowp   = (int*)alloc((size_t)(N + 1) * 4);
    int* pos    = (int*)alloc((size_t)N * 4);
    int* srcs   = (int*)alloc((size_t)E * 4);
    int* gstart = (int*)alloc(65 * 4);
    int* bsum   = (int*)alloc(1024 * 4);
    int* boff   = (int*)alloc(1024 * 4);
    float* partial = (float*)alloc((size_t)512 * 64 * 4);

    hipMemsetAsync(cnt, 0, (size_t)N * 4, stream);

    const int TB = 256;
    const int nwb = (N + 3) / 4;
    const int nsb = (N + 1023) / 1024;
    const int span = (N + 7) / 8;

    hist_kernel<<<1024, TB, 0, stream>>>(dst, cnt, E, span);
    scan1_kernel<<<nsb, TB, 0, stream>>>(cnt, bsum, N);
    scan2_kernel<<<1, TB, 0, stream>>>(bsum, boff, nsb);
    scan3_kernel<<<nsb, TB, 0, stream>>>(cnt, boff, rowp, pos, N);
    scatter_kernel<<<1024, TB, 0, stream>>>(src, dst, pos, srcs, E, span);
    bounds_kernel<<<1, 128, 0, stream>>>(batch, gstart, N);

    conv_weights_kernel<<<576, TB, 0, stream>>>(W_rel0, W_root0, W_rel1, W_root1,
                                                W_rel2, W_root2, Wt0, WtC1, WtC2);
    conv_x_kernel<<<(N * 128 / 4 + TB - 1) / TB, TB, 0, stream>>>(x, xb16, N * 128 / 4);

    const int gx = (N + 63) / 64;

    // layer 0: agg(x) -> [agg|x] @ Wt0 (+bias,BN,ReLU) -> h0 [N,256]
    agg_bf16<128><<<nwb, TB, 0, stream>>>(xb16, 128, nullptr, 0, rowp, srcs,
                                          nullptr, nullptr, nullptr, nullptr, nullptr,
                                          aggb16, N);
    gemm_mfma<<<dim3(gx, 2), TB, 0, stream>>>(aggb16, xb16, Wt0,
                                              b_rel0, bn_g0, bn_b0, bn_m0, bn_v0,
                                              h0, nullptr, 0, N, 256, 256);

    // layer 1: yrel/yroot = h0 @ [Wrel1|Wroot1]; h1 = bnrelu(agg(yrel)+yroot+b)
    gemm_mfma<<<dim3(gx, 2), TB, 0, stream>>>(h0, nullptr, WtC1,
                                              nullptr, nullptr, nullptr, nullptr, nullptr,
                                              yrel, yroot, 128, N, 256, 256);
    agg_bf16<128><<<nwb, TB, 0, stream>>>(yrel, 128, yroot, 128, rowp, srcs,
                                          b_rel1, bn_g1, bn_b1, bn_m1, bn_v1,
                                          h1, N);

    // layer 2: yrel/yroot = h1 @ [Wrel2|Wroot2]; h2 = bnrelu(agg+root+b)
    gemm_mfma<<<dim3(gx, 1), TB, 0, stream>>>(h1, nullptr, WtC2,
                                              nullptr, nullptr, nullptr, nullptr, nullptr,
                                              yrel, yroot, 64, N, 128, 128);
    agg_bf16<64><<<nwb, TB, 0, stream>>>(yrel, 64, yroot, 64, rowp, srcs,
                                         b_rel2, bn_g2, bn_b2, bn_m2, bn_v2,
                                         h2, N);

    // mean pool + head (two-phase)
    pool_part_kernel<<<512, TB, 0, stream>>>(h2, gstart, partial);
    head_final_kernel<<<64, 64, 0, stream>>>(partial, gstart, W_out, b_out, (float*)d_out);
}

// Round 9
// 279.919 us; speedup vs baseline: 1.4670x; 1.0411x over previous
//
#include <hip/hip_runtime.h>

// GeneticDosageGNN: 3x GraphConv(+BN+ReLU) -> mean pool -> linear head
// N=50000 nodes, E=800000 edges, dims 128->256->128->64->3, 64 graphs.
// R9: fuse GEMM0+BN0+GEMM1 (h0 never leaves LDS); agg unroll 8 (latency probe).

typedef __attribute__((ext_vector_type(8))) short    bf16x8;
typedef __attribute__((ext_vector_type(4))) float    f32x4;
typedef __attribute__((ext_vector_type(8))) unsigned short ush8;
typedef __attribute__((ext_vector_type(4))) unsigned short ush4;

__device__ __forceinline__ unsigned short f2b(float f) {
    union { float f; unsigned int u; } c; c.f = f;
    unsigned int u = c.u;
    return (unsigned short)((u + 0x7fffu + ((u >> 16) & 1u)) >> 16);
}
__device__ __forceinline__ float b2f(unsigned short h) {
    union { unsigned int u; float f; } c; c.u = ((unsigned int)h) << 16;
    return c.f;
}
__device__ __forceinline__ float blo(unsigned int u) { return b2f((unsigned short)(u & 0xffff)); }
__device__ __forceinline__ float bhi(unsigned int u) { return b2f((unsigned short)(u >> 16)); }

// ---------------- CSR build (XCD-partitioned by dst range) ----------------

__global__ __launch_bounds__(256)
void hist_kernel(const int* __restrict__ dst, int* __restrict__ cnt, int E, int span) {
    int grp = blockIdx.x & 7;
    int bid = blockIdx.x >> 3;
    int nb = gridDim.x >> 3;
    int lo = grp * span, hi = lo + span;
    for (int i = bid * 256 + threadIdx.x; i < E; i += nb * 256) {
        int d = dst[i];
        if (d >= lo && d < hi) atomicAdd(&cnt[d], 1);
    }
}

__global__ __launch_bounds__(256)
void scan1_kernel(const int* __restrict__ cnt, int* __restrict__ bsum, int N) {
    __shared__ int red[256];
    int base = blockIdx.x * 1024;
    int t = threadIdx.x;
    int s = 0;
#pragma unroll
    for (int j = 0; j < 4; ++j) {
        int i = base + t * 4 + j;
        if (i < N) s += cnt[i];
    }
    red[t] = s;
    __syncthreads();
    for (int d = 128; d > 0; d >>= 1) {
        if (t < d) red[t] += red[t + d];
        __syncthreads();
    }
    if (t == 0) bsum[blockIdx.x] = red[0];
}

__global__ void scan2_kernel(const int* __restrict__ bsum, int* __restrict__ boff, int nb) {
    __shared__ int v[1024];
    int t = threadIdx.x;
    for (int i = t; i < nb; i += 256) v[i] = bsum[i];
    __syncthreads();
    if (t == 0) {
        int run = 0;
        for (int i = 0; i < nb; ++i) { int c = v[i]; v[i] = run; run += c; }
    }
    __syncthreads();
    for (int i = t; i < nb; i += 256) boff[i] = v[i];
}

__global__ __launch_bounds__(256)
void scan3_kernel(const int* __restrict__ cnt, const int* __restrict__ boff,
                  int* __restrict__ rowptr, int* __restrict__ pos, int N) {
    __shared__ int wsum[4];
    int base = blockIdx.x * 1024;
    int t = threadIdx.x;
    int lane = t & 63, wv = t >> 6;
    int c[4];
    int s = 0;
#pragma unroll
    for (int j = 0; j < 4; ++j) {
        int i = base + t * 4 + j;
        c[j] = (i < N) ? cnt[i] : 0;
        s += c[j];
    }
    int val = s;
#pragma unroll
    for (int d = 1; d < 64; d <<= 1) {
        int o = __shfl_up(val, d, 64);
        if (lane >= d) val += o;
    }
    if (lane == 63) wsum[wv] = val;
    __syncthreads();
    int wadd = 0;
    for (int i = 0; i < wv; ++i) wadd += wsum[i];
    int excl = val - s + wadd + boff[blockIdx.x];
#pragma unroll
    for (int j = 0; j < 4; ++j) {
        int i = base + t * 4 + j;
        if (i < N) {
            rowptr[i] = excl;
            pos[i] = excl;
            excl += c[j];
            if (i == N - 1) rowptr[N] = excl;
        }
    }
}

__global__ __launch_bounds__(256)
void scatter_kernel(const int* __restrict__ src, const int* __restrict__ dst,
                    int* __restrict__ pos, int* __restrict__ srcs, int E, int span) {
    int grp = blockIdx.x & 7;
    int bid = blockIdx.x >> 3;
    int nb = gridDim.x >> 3;
    int lo = grp * span, hi = lo + span;
    for (int i = bid * 256 + threadIdx.x; i < E; i += nb * 256) {
        int d = dst[i];
        if (d >= lo && d < hi) {
            int p = atomicAdd(&pos[d], 1);
            srcs[p] = src[i];
        }
    }
}

__global__ void bounds_kernel(const int* __restrict__ batch, int* __restrict__ start, int N) {
    int g = threadIdx.x;
    if (g > 64) return;
    int lo = 0, hi = N;
    while (lo < hi) {
        int mid = (lo + hi) >> 1;
        if (batch[mid] < g) lo = mid + 1; else hi = mid;
    }
    start[g] = lo;
}

// ---------------- conversions ----------------

__global__ __launch_bounds__(256)
void conv_x_kernel(const float* __restrict__ x, unsigned short* __restrict__ xb, int n4) {
    int i = blockIdx.x * 256 + threadIdx.x;
    if (i >= n4) return;
    float4 v = ((const float4*)x)[i];
    ush4 o = { f2b(v.x), f2b(v.y), f2b(v.z), f2b(v.w) };
    *(ush4*)(xb + (size_t)i * 4) = o;
}

__global__ __launch_bounds__(256)
void conv_weights_kernel(const float* __restrict__ Wrel0, const float* __restrict__ Wroot0,
                         const float* __restrict__ Wrel1, const float* __restrict__ Wroot1,
                         const float* __restrict__ Wrel2, const float* __restrict__ Wroot2,
                         unsigned short* __restrict__ Wt0,
                         unsigned short* __restrict__ WtC1,
                         unsigned short* __restrict__ WtC2) {
    int i = blockIdx.x * 256 + threadIdx.x;
    if (i < 65536) {
        int m = i >> 8, k = i & 255;
        float v = (k < 128) ? Wrel0[k * 256 + m] : Wroot0[(k - 128) * 256 + m];
        Wt0[i] = f2b(v);
    } else if (i < 131072) {
        int j = i - 65536;
        int m = j >> 8, k = j & 255;
        float v = (m < 128) ? Wrel1[k * 128 + m] : Wroot1[k * 128 + (m - 128)];
        WtC1[j] = f2b(v);
    } else if (i < 147456) {
        int j = i - 131072;
        int m = j >> 7, k = j & 127;
        float v = (m < 64) ? Wrel2[k * 64 + m] : Wroot2[k * 64 + (m - 64)];
        WtC2[j] = f2b(v);
    }
}

// ---------------- aggregation over CSR (+root/bias/BN/ReLU), bf16 ----------

template<int F>
__global__ __launch_bounds__(256)
void agg_bf16(const unsigned short* __restrict__ ysrc, int ystride,
              const unsigned short* __restrict__ yroot, int rstride,
              const int* __restrict__ rowptr, const int* __restrict__ srcs,
              const float* __restrict__ bias,
              const float* __restrict__ bng, const float* __restrict__ bnb,
              const float* __restrict__ bnm, const float* __restrict__ bnv,
              unsigned short* __restrict__ out, int N)
{
    int w = (blockIdx.x * blockDim.x + threadIdx.x) >> 6;
    int lane = threadIdx.x & 63;
    if (w >= N) return;
    int beg = rowptr[w], end = rowptr[w + 1];

    if (F == 128) {
        float p0[8] = {}, p1[8] = {};
        int e = beg;
        for (; e + 7 < end; e += 8) {
            unsigned int u[8];
#pragma unroll
            for (int q = 0; q < 8; ++q)
                u[q] = *(const unsigned int*)(ysrc + (size_t)srcs[e + q] * ystride + lane * 2);
#pragma unroll
            for (int q = 0; q < 8; ++q) { p0[q] += blo(u[q]); p1[q] += bhi(u[q]); }
        }
        for (; e < end; ++e) {
            unsigned int u = *(const unsigned int*)(ysrc + (size_t)srcs[e] * ystride + lane * 2);
            p0[0] += blo(u); p1[0] += bhi(u);
        }
        float a0 = ((p0[0] + p0[1]) + (p0[2] + p0[3])) + ((p0[4] + p0[5]) + (p0[6] + p0[7]));
        float a1 = ((p1[0] + p1[1]) + (p1[2] + p1[3])) + ((p1[4] + p1[5]) + (p1[6] + p1[7]));

        int f0 = lane * 2, f1 = lane * 2 + 1;
        if (yroot) {
            unsigned int u = *(const unsigned int*)(yroot + (size_t)w * rstride + lane * 2);
            a0 += blo(u); a1 += bhi(u);
        }
        if (bias) {
            a0 += bias[f0]; a1 += bias[f1];
            a0 = (a0 - bnm[f0]) * rsqrtf(bnv[f0] + 1e-5f) * bng[f0] + bnb[f0];
            a1 = (a1 - bnm[f1]) * rsqrtf(bnv[f1] + 1e-5f) * bng[f1] + bnb[f1];
            a0 = fmaxf(a0, 0.f); a1 = fmaxf(a1, 0.f);
        }
        unsigned int o = (unsigned int)f2b(a0) | ((unsigned int)f2b(a1) << 16);
        *(unsigned int*)(out + (size_t)w * 128 + lane * 2) = o;
    } else {  // F == 64: lanes 0-31 take even-offset edges, 32-63 odd
        int half = lane >> 5;
        int lr = lane & 31;
        float a0 = 0.f, a1 = 0.f, b0 = 0.f, b1 = 0.f;
        int e = beg + half;
        for (; e + 2 < end; e += 4) {
            int s0 = srcs[e], s1 = srcs[e + 2];
            unsigned int u0 = *(const unsigned int*)(ysrc + (size_t)s0 * ystride + lr * 2);
            unsigned int u1 = *(const unsigned int*)(ysrc + (size_t)s1 * ystride + lr * 2);
            a0 += blo(u0); a1 += bhi(u0);
            b0 += blo(u1); b1 += bhi(u1);
        }
        if (e < end) {
            unsigned int u = *(const unsigned int*)(ysrc + (size_t)srcs[e] * ystride + lr * 2);
            a0 += blo(u); a1 += bhi(u);
        }
        a0 += b0; a1 += b1;
        a0 += __shfl_xor(a0, 32, 64);
        a1 += __shfl_xor(a1, 32, 64);

        if (half == 0) {
            int f0 = lr * 2, f1 = lr * 2 + 1;
            if (yroot) {
                unsigned int u = *(const unsigned int*)(yroot + (size_t)w * rstride + lr * 2);
                a0 += blo(u); a1 += bhi(u);
            }
            if (bias) {
                a0 += bias[f0]; a1 += bias[f1];
                a0 = (a0 - bnm[f0]) * rsqrtf(bnv[f0] + 1e-5f) * bng[f0] + bnb[f0];
                a1 = (a1 - bnm[f1]) * rsqrtf(bnv[f1] + 1e-5f) * bng[f1] + bnb[f1];
                a0 = fmaxf(a0, 0.f); a1 = fmaxf(a1, 0.f);
            }
            unsigned int o = (unsigned int)f2b(a0) | ((unsigned int)f2b(a1) << 16);
            *(unsigned int*)(out + (size_t)w * 64 + lr * 2) = o;
        }
    }
}

// ---------------- fused layer0-GEMM + BN/ReLU + layer1-GEMM -----------------
// Per block: 64 rows. Phase 1: h0 = bnrelu([agg|x] @ Wt0^T + b0)  (64x256, LDS)
//            Phase 2: [yrel|yroot] = h0 @ WtC1^T                  (64x256, global)
// 4 waves, wave w owns rows 16w..16w+15 in both phases. LDS 64KB union.

__global__ __launch_bounds__(256)
void gemm_fused01(const unsigned short* __restrict__ aggb,
                  const unsigned short* __restrict__ xb,
                  const unsigned short* __restrict__ Wt0,   // [256][256]
                  const unsigned short* __restrict__ WtC1,  // [256][256]
                  const float* __restrict__ bias,
                  const float* __restrict__ bng, const float* __restrict__ bnb,
                  const float* __restrict__ bnm, const float* __restrict__ bnv,
                  unsigned short* __restrict__ yrel, unsigned short* __restrict__ yroot,
                  int N)
{
    __shared__ unsigned short smem[32768];          // 64 KB
    unsigned short* As  = smem;                     // [64][64]   (phase 1)
    unsigned short* Ws0 = smem + 4096;              // [256][64]  (phase 1)
    unsigned short* H   = smem;                     // [64][256]  (phase 2, overlaps As+Ws0)
    unsigned short* Ws1 = smem + 16384;             // [256][64]  (phase 2)

    const int tid = threadIdx.x;
    const int n0 = blockIdx.x * 64;
    const int wv = tid >> 6, lane = tid & 63;
    const int lr = lane & 15, lg = lane >> 4;
    const int swl = (lr & 7) << 3;                  // element swizzle for reads

    f32x4 acc[16];
#pragma unroll
    for (int j = 0; j < 16; ++j) acc[j] = (f32x4){0.f, 0.f, 0.f, 0.f};

    // -------- phase 1: [agg|x](64x256) @ Wt0 --------
    for (int k0 = 0; k0 < 256; k0 += 64) {
        // stage A (64x64): 512 ush8 slots
#pragma unroll
        for (int it = 0; it < 2; ++it) {
            int c = tid + it * 256;
            int row = c >> 3;
            int kb = (c & 7) << 3;
            int sw = kb ^ ((row & 7) << 3);
            int n = n0 + row;
            int ksrc = k0 + kb;
            const unsigned short* Ap = (ksrc < 128) ? aggb : xb;
            int kl = (ksrc < 128) ? ksrc : ksrc - 128;
            ush8 va = {};
            if (n < N) va = *(const ush8*)(Ap + (size_t)n * 128 + kl);
            *(ush8*)&As[row * 64 + sw] = va;
        }
        // stage Ws0 (256x64): 2048 ush8 slots
#pragma unroll
        for (int it = 0; it < 8; ++it) {
            int c = tid + it * 256;
            int row = c >> 3;
            int kb = (c & 7) << 3;
            int sw = kb ^ ((row & 7) << 3);
            ush8 vw = *(const ush8*)(Wt0 + (size_t)row * 256 + k0 + kb);
            *(ush8*)&Ws0[row * 64 + sw] = vw;
        }
        __syncthreads();
#pragma unroll
        for (int s = 0; s < 2; ++s) {
            int kk = s * 32 + lg * 8;
            int row = wv * 16 + lr;
            bf16x8 af = *(const bf16x8*)&As[row * 64 + (kk ^ swl)];
#pragma unroll
            for (int j = 0; j < 16; ++j) {
                int wr = j * 16 + lr;
                bf16x8 bfr = *(const bf16x8*)&Ws0[wr * 64 + (kk ^ swl)];
                acc[j] = __builtin_amdgcn_mfma_f32_16x16x32_bf16(af, bfr, acc[j], 0, 0, 0);
            }
        }
        __syncthreads();
    }

    // -------- phase 1 epilogue: BN/ReLU -> H (swizzled LDS) --------
#pragma unroll
    for (int j = 0; j < 16; ++j) {
#pragma unroll
        for (int r = 0; r < 4; ++r) {
            int row = wv * 16 + lg * 4 + r;
            int col = j * 16 + lr;
            float val = acc[j][r] + bias[col];
            val = (val - bnm[col]) * rsqrtf(bnv[col] + 1e-5f) * bng[col] + bnb[col];
            val = fmaxf(val, 0.f);
            H[row * 256 + (col ^ ((row & 7) << 3))] = f2b(val);
        }
        acc[j] = (f32x4){0.f, 0.f, 0.f, 0.f};
    }
    __syncthreads();

    // -------- phase 2: H(64x256) @ WtC1 --------
    for (int k0 = 0; k0 < 256; k0 += 64) {
#pragma unroll
        for (int it = 0; it < 8; ++it) {
            int c = tid + it * 256;
            int row = c >> 3;
            int kb = (c & 7) << 3;
            int sw = kb ^ ((row & 7) << 3);
            ush8 vw = *(const ush8*)(WtC1 + (size_t)row * 256 + k0 + kb);
            *(ush8*)&Ws1[row * 64 + sw] = vw;
        }
        __syncthreads();
#pragma unroll
        for (int s = 0; s < 2; ++s) {
            int kk = s * 32 + lg * 8;
            int row = wv * 16 + lr;
            bf16x8 af = *(const bf16x8*)&H[row * 256 + ((k0 + kk) ^ swl)];
#pragma unroll
            for (int j = 0; j < 16; ++j) {
                int wr = j * 16 + lr;
                bf16x8 bfr = *(const bf16x8*)&Ws1[wr * 64 + (kk ^ swl)];
                acc[j] = __builtin_amdgcn_mfma_f32_16x16x32_bf16(af, bfr, acc[j], 0, 0, 0);
            }
        }
        __syncthreads();
    }

    // -------- phase 2 epilogue: split write yrel / yroot --------
#pragma unroll
    for (int j = 0; j < 16; ++j) {
#pragma unroll
        for (int r = 0; r < 4; ++r) {
            int row = n0 + wv * 16 + lg * 4 + r;
            if (row >= N) continue;
            int col = j * 16 + lr;
            unsigned short hv = f2b(acc[j][r]);
            if (col < 128) yrel[(size_t)row * 128 + col] = hv;
            else           yroot[(size_t)row * 128 + col - 128] = hv;
        }
    }
}

// ---------------- generic GEMM (layer 2): tile 64x128, BK=64 ----------------

__global__ __launch_bounds__(256)
void gemm_mfma(const unsigned short* __restrict__ A1,
               const unsigned short* __restrict__ Wt,
               unsigned short* __restrict__ C, unsigned short* __restrict__ C2,
               int csplit, int N, int Ktot, int M)
{
    __shared__ unsigned short As[64][64];
    __shared__ unsigned short Ws[128][64];

    const int tid = threadIdx.x;
    const int n0 = blockIdx.x * 64;
    const int m0 = blockIdx.y * 128;
    const int wid = tid >> 6, lane = tid & 63;
    const int wm = wid >> 1, wn = wid & 1;
    const int lr = lane & 15, lg = lane >> 4;

    f32x4 acc[2][4] = {};

    for (int k0 = 0; k0 < Ktot; k0 += 64) {
#pragma unroll
        for (int it = 0; it < 2; ++it) {
            int c = tid + it * 256;
            int row = c >> 3;
            int kb = (c & 7) << 3;
            int sw = kb ^ ((row & 7) << 3);
            int n = n0 + row;
            ush8 va = {};
            if (n < N) va = *(const ush8*)(A1 + (size_t)n * Ktot + k0 + kb);
            *(ush8*)&As[row][sw] = va;
        }
#pragma unroll
        for (int it = 0; it < 4; ++it) {
            int c = tid + it * 256;
            int row = c >> 3;
            int kb = (c & 7) << 3;
            int sw = kb ^ ((row & 7) << 3);
            ush8 vw = *(const ush8*)(Wt + (size_t)(m0 + row) * Ktot + k0 + kb);
            *(ush8*)&Ws[row][sw] = vw;
        }
        __syncthreads();
#pragma unroll
        for (int s = 0; s < 2; ++s) {
            int kk = s * 32 + lg * 8;
            bf16x8 af[2], bfr[4];
#pragma unroll
            for (int i = 0; i < 2; ++i) {
                int row = wm * 32 + i * 16 + lr;
                af[i] = *(const bf16x8*)&As[row][kk ^ ((row & 7) << 3)];
            }
#pragma unroll
            for (int j = 0; j < 4; ++j) {
                int wr = wn * 64 + j * 16 + lr;
                bfr[j] = *(const bf16x8*)&Ws[wr][kk ^ ((wr & 7) << 3)];
            }
#pragma unroll
            for (int i = 0; i < 2; ++i)
#pragma unroll
                for (int j = 0; j < 4; ++j)
                    acc[i][j] = __builtin_amdgcn_mfma_f32_16x16x32_bf16(af[i], bfr[j], acc[i][j], 0, 0, 0);
        }
        __syncthreads();
    }

#pragma unroll
    for (int i = 0; i < 2; ++i) {
#pragma unroll
        for (int r = 0; r < 4; ++r) {
            int row = n0 + wm * 32 + i * 16 + lg * 4 + r;
            if (row >= N) continue;
#pragma unroll
            for (int j = 0; j < 4; ++j) {
                int col = m0 + wn * 64 + j * 16 + lr;
                float val = acc[i][j][r];
                unsigned short* Cp;
                if (col < csplit) Cp = C + (size_t)row * csplit + col;
                else              Cp = C2 + (size_t)row * (M - csplit) + (col - csplit);
                *Cp = f2b(val);
            }
        }
    }
}

// ---------------- pooling + head (two-phase, batch sorted) ------------------

__global__ __launch_bounds__(256)
void pool_part_kernel(const unsigned short* __restrict__ h, const int* __restrict__ start,
                      float* __restrict__ partial) {
    int g = blockIdx.x >> 3, c = blockIdx.x & 7;
    int f = threadIdx.x & 63, sub = threadIdx.x >> 6;
    int beg = start[g], end = start[g + 1];
    int cnt = end - beg;
    int cbeg = beg + (int)(((long long)cnt * c) >> 3);
    int cend = beg + (int)(((long long)cnt * (c + 1)) >> 3);
    float acc = 0.f;
    for (int n = cbeg + sub; n < cend; n += 4)
        acc += b2f(h[(size_t)n * 64 + f]);
    __shared__ float red[4][64];
    red[sub][f] = acc;
    __syncthreads();
    if (sub == 0)
        partial[(size_t)blockIdx.x * 64 + f] = red[0][f] + red[1][f] + red[2][f] + red[3][f];
}

__global__ void head_final_kernel(const float* __restrict__ partial, const int* __restrict__ start,
                                  const float* __restrict__ Wout, const float* __restrict__ bout,
                                  float* __restrict__ out) {
    int g = blockIdx.x;
    int f = threadIdx.x;
    float s = 0.f;
#pragma unroll
    for (int c = 0; c < 8; ++c) s += partial[(size_t)(g * 8 + c) * 64 + f];
    float cnt = fmaxf((float)(start[g + 1] - start[g]), 1.0f);
    __shared__ float red[64];
    red[f] = s / cnt;
    __syncthreads();
    if (f < 3) {
        float acc = 0.f;
#pragma unroll
        for (int k = 0; k < 64; ++k) acc += red[k] * Wout[k * 3 + f];
        out[g * 3 + f] = acc + bout[f];
    }
}

// ---------------- launch ----------------------------------------------------

extern "C" void kernel_launch(void* const* d_in, const int* in_sizes, int n_in,
                              void* d_out, int out_size, void* d_ws, size_t ws_size,
                              hipStream_t stream)
{
    const float* x       = (const float*)d_in[0];
    const int*   ei      = (const int*)d_in[1];
    const int*   batch   = (const int*)d_in[2];
    const float* W_rel0  = (const float*)d_in[3];
    const float* b_rel0  = (const float*)d_in[4];
    const float* W_root0 = (const float*)d_in[5];
    const float* bn_g0   = (const float*)d_in[6];
    const float* bn_b0   = (const float*)d_in[7];
    const float* bn_m0   = (const float*)d_in[8];
    const float* bn_v0   = (const float*)d_in[9];
    const float* W_rel1  = (const float*)d_in[10];
    const float* b_rel1  = (const float*)d_in[11];
    const float* W_root1 = (const float*)d_in[12];
    const float* bn_g1   = (const float*)d_in[13];
    const float* bn_b1   = (const float*)d_in[14];
    const float* bn_m1   = (const float*)d_in[15];
    const float* bn_v1   = (const float*)d_in[16];
    const float* W_rel2  = (const float*)d_in[17];
    const float* b_rel2  = (const float*)d_in[18];
    const float* W_root2 = (const float*)d_in[19];
    const float* bn_g2   = (const float*)d_in[20];
    const float* bn_b2   = (const float*)d_in[21];
    const float* bn_m2   = (const float*)d_in[22];
    const float* bn_v2   = (const float*)d_in[23];
    const float* W_out   = (const float*)d_in[24];
    const float* b_out   = (const float*)d_in[25];

    const int N = in_sizes[0] / 128;
    const int E = in_sizes[1] / 2;
    const int* src = ei;
    const int* dst = ei + E;

    char* ws = (char*)d_ws;
    size_t off = 0;
    auto alloc = [&](size_t b) -> void* {
        off = (off + 255) & ~(size_t)255;
        void* p = ws + off;
        off += b;
        return p;
    };

    unsigned short* xb16   = (unsigned short*)alloc((size_t)N * 128 * 2);
    unsigned short* aggb16 = (unsigned short*)alloc((size_t)N * 128 * 2);
    unsigned short* yrel   = (unsigned short*)alloc((size_t)N * 128 * 2);
    unsigned short* yroot  = (unsigned short*)alloc((size_t)N * 128 * 2);
    unsigned short* h1     = (unsigned short*)alloc((size_t)N * 128 * 2);
    unsigned short* h2     = (unsigned short*)alloc((size_t)N * 64 * 2);
    unsigned short* Wt0    = (unsigned short*)alloc(256 * 256 * 2);
    unsigned short* WtC1   = (unsigned short*)alloc(256 * 256 * 2);
    unsigned short* WtC2   = (unsigned short*)alloc(128 * 128 * 2);
    int* cnt    = (int*)alloc((size_t)N * 4);
    int* rowp   = (int*)alloc((size_t)(N + 1) * 4);
    int* pos    = (int*)alloc((size_t)N * 4);
    int* srcs   = (int*)alloc((size_t)E * 4);
    int* gstart = (int*)alloc(65 * 4);
    int* bsum   = (int*)alloc(1024 * 4);
    int* boff   = (int*)alloc(1024 * 4);
    float* partial = (float*)alloc((size_t)512 * 64 * 4);

    hipMemsetAsync(cnt, 0, (size_t)N * 4, stream);

    const int TB = 256;
    const int nwb = (N + 3) / 4;
    const int nsb = (N + 1023) / 1024;
    const int span = (N + 7) / 8;

    hist_kernel<<<1024, TB, 0, stream>>>(dst, cnt, E, span);
    scan1_kernel<<<nsb, TB, 0, stream>>>(cnt, bsum, N);
    scan2_kernel<<<1, TB, 0, stream>>>(bsum, boff, nsb);
    scan3_kernel<<<nsb, TB, 0, stream>>>(cnt, boff, rowp, pos, N);
    scatter_kernel<<<1024, TB, 0, stream>>>(src, dst, pos, srcs, E, span);
    bounds_kernel<<<1, 128, 0, stream>>>(batch, gstart, N);

    conv_weights_kernel<<<576, TB, 0, stream>>>(W_rel0, W_root0, W_rel1, W_root1,
                                                W_rel2, W_root2, Wt0, WtC1, WtC2);
    conv_x_kernel<<<(N * 128 / 4 + TB - 1) / TB, TB, 0, stream>>>(x, xb16, N * 128 / 4);

    const int gx = (N + 63) / 64;

    // layer 0+1 GEMMs fused: agg(x) -> h0 (LDS only) -> yrel/yroot
    agg_bf16<128><<<nwb, TB, 0, stream>>>(xb16, 128, nullptr, 0, rowp, srcs,
                                          nullptr, nullptr, nullptr, nullptr, nullptr,
                                          aggb16, N);
    gemm_fused01<<<gx, TB, 0, stream>>>(aggb16, xb16, Wt0, WtC1,
                                        b_rel0, bn_g0, bn_b0, bn_m0, bn_v0,
                                        yrel, yroot, N);
    agg_bf16<128><<<nwb, TB, 0, stream>>>(yrel, 128, yroot, 128, rowp, srcs,
                                          b_rel1, bn_g1, bn_b1, bn_m1, bn_v1,
                                          h1, N);

    // layer 2: yrel/yroot = h1 @ [Wrel2|Wroot2]; h2 = bnrelu(agg+root+b)
    gemm_mfma<<<dim3(gx, 1), TB, 0, stream>>>(h1, WtC2, yrel, yroot, 64, N, 128, 128);
    agg_bf16<64><<<nwb, TB, 0, stream>>>(yrel, 64, yroot, 64, rowp, srcs,
                                         b_rel2, bn_g2, bn_b2, bn_m2, bn_v2,
                                         h2, N);

    // mean pool + head (two-phase)
    pool_part_kernel<<<512, TB, 0, stream>>>(h2, gstart, partial);
    head_final_kernel<<<64, 64, 0, stream>>>(partial, gstart, W_out, b_out, (float*)d_out);
}